// Round 8
// baseline (543.294 us; speedup 1.0000x reference)
//
#include <hip/hip_runtime.h>
#include <math.h>

// Problem dims
#define B_   48
#define W_   88
#define C_   256
#define H_   32
#define F_   1024
#define BW_  (B_ * W_)        // 4224
#define BWH_ (B_ * W_ * H_)   // 135168
#define HW_  (H_ * W_)        // 2816
#define NPSTR 2064            // partial row stride (2048 numer + 8 l + pad)

typedef float  f32x4  __attribute__((ext_vector_type(4)));
typedef __bf16 bf16x8 __attribute__((ext_vector_type(8)));

__device__ __forceinline__ unsigned short f2bf(float f) {
  union { float f; unsigned int u; } v; v.f = f;
  unsigned int r = v.u + 0x7FFFu + ((v.u >> 16) & 1u);  // RNE
  return (unsigned short)(r >> 16);
}
__device__ __forceinline__ float bf2f(unsigned short h) {
  union { unsigned int u; float f; } v; v.u = ((unsigned int)h) << 16;
  return v.f;
}
__device__ __forceinline__ unsigned int pack2(float a, float b) {
  return (unsigned int)f2bf(a) | ((unsigned int)f2bf(b) << 16);
}

// ---------------------------------------------------------------------------
// prep_all: every weight-prep step in ONE launch.
//  blk [0,768)      : 32x32 LDS tile transposes f32[in,out] -> bf16[out,in]
//  blk [768,1280)   : Mqk build  (512 blocks: h x 64 c-chunks of 4)
//  blk [1280,1792)  : Mvp build  (512 blocks: h x 64 d-chunks of 4)
//  blk 1792         : bvp + bqkvs concat
//  blk [1793,6017)  : LN(pooled) -> qn_c bf16 (one row per block)
//  blk 6017         : cross_pe row sums (pes[2h]=sum, pes[2h+1]=sumsq)
// ---------------------------------------------------------------------------
__global__ __launch_bounds__(256) void prep_all(
    const float* __restrict__ Wq_s, const float* __restrict__ Wk_s,
    const float* __restrict__ Wv_s, const float* __restrict__ Wp_s,
    const float* __restrict__ W1, const float* __restrict__ W2,
    const float* __restrict__ Wq_c, const float* __restrict__ Wk_c,
    const float* __restrict__ Wv_c, const float* __restrict__ Wp_c,
    const float* __restrict__ bq_s, const float* __restrict__ bv_s,
    const float* __restrict__ bq_c, const float* __restrict__ bv_c,
    const float* __restrict__ bp_c,
    const float* __restrict__ pooled,
    const float* __restrict__ ln_qc_g, const float* __restrict__ ln_qc_b,
    const float* __restrict__ cross_pe,
    unsigned short* __restrict__ wqkvs, unsigned short* __restrict__ wps,
    unsigned short* __restrict__ w1t, unsigned short* __restrict__ w2t,
    unsigned short* __restrict__ mqk, unsigned short* __restrict__ mvp,
    float* __restrict__ bqk, float* __restrict__ bvp,
    float* __restrict__ bqkvs, unsigned short* __restrict__ qn_c,
    float* __restrict__ pes) {
  __shared__ float smem[256 * 33 + 4 * 33];
  int blk = blockIdx.x, t = threadIdx.x;

  if (blk < 768) {
    // ---- weight tile transpose ----
    const float* src; unsigned short* dst; int Cc, R, tile;
    if (blk < 64)       { src = Wq_s; dst = wqkvs;          Cc = 256;  R = 256;  tile = blk; }
    else if (blk < 128) { src = Wk_s; dst = wqkvs + 65536;  Cc = 256;  R = 256;  tile = blk - 64; }
    else if (blk < 192) { src = Wv_s; dst = wqkvs + 131072; Cc = 256;  R = 256;  tile = blk - 128; }
    else if (blk < 256) { src = Wp_s; dst = wps;            Cc = 256;  R = 256;  tile = blk - 192; }
    else if (blk < 512) { src = W1;   dst = w1t;            Cc = 1024; R = 256;  tile = blk - 256; }
    else                { src = W2;   dst = w2t;            Cc = 256;  R = 1024; tile = blk - 512; }
    int tcn = Cc >> 5;
    int tr = tile / tcn, tc = tile % tcn;
    float (*lds)[33] = (float(*)[33])smem;
    int r = t >> 3, c4 = (t & 7) * 4;
    float4 v = *(const float4*)(src + (size_t)(tr * 32 + r) * Cc + tc * 32 + c4);
    lds[r][c4 + 0] = v.x; lds[r][c4 + 1] = v.y; lds[r][c4 + 2] = v.z; lds[r][c4 + 3] = v.w;
    __syncthreads();
    // dst[(tc*32+rd)][tr*32 + cd] = src[tr*32+cd][tc*32+rd]
    int rd = t >> 3, cd4 = (t & 7) * 4;
    unsigned int u0 = pack2(lds[cd4 + 0][rd], lds[cd4 + 1][rd]);
    unsigned int u1 = pack2(lds[cd4 + 2][rd], lds[cd4 + 3][rd]);
    uint2 u; u.x = u0; u.y = u1;
    *(uint2*)(dst + (size_t)(tc * 32 + rd) * R + tr * 32 + cd4) = u;
  } else if (blk < 1280) {
    // ---- Mqk[n=256h+c][dp] = scale * sum_dd Wq_c[dp,32h+dd]*Wk_c[c,32h+dd]
    int lb = blk - 768;
    int h = lb >> 6, cb = lb & 63;
    float (*wq)[33] = (float(*)[33])smem;               // [256 dp][32 dd]
    float (*wk)[33] = (float(*)[33])(smem + 256 * 33);  // [4 c][32 dd]
#pragma unroll
    for (int p = 0; p < 8; p++) {
      int dp = (t >> 3) + 32 * p, d4 = (t & 7) * 4;
      float4 v = *(const float4*)(Wq_c + (size_t)dp * 256 + 32 * h + d4);
      wq[dp][d4 + 0] = v.x; wq[dp][d4 + 1] = v.y; wq[dp][d4 + 2] = v.z; wq[dp][d4 + 3] = v.w;
    }
    if (t < 128) {
      int c_l = t >> 5, dd = t & 31;
      wk[c_l][dd] = Wk_c[(size_t)(cb * 4 + c_l) * 256 + 32 * h + dd];
    }
    __syncthreads();
    const float scale = 0.17677669529663689f;
    int c_l = t >> 6, ln = t & 63;
    int n = 256 * h + cb * 4 + c_l;
#pragma unroll
    for (int j = 0; j < 4; j++) {
      int dp = ln + 64 * j;
      float acc = 0.f;
#pragma unroll
      for (int dd = 0; dd < 32; dd++) acc += wq[dp][dd] * wk[c_l][dd];
      mqk[(size_t)n * 256 + dp] = f2bf(acc * scale);
    }
    if (ln == 0) {
      float bb = 0.f;
#pragma unroll
      for (int dd = 0; dd < 32; dd++) bb += bq_c[32 * h + dd] * wk[c_l][dd];
      bqk[n] = bb * scale;
    }
  } else if (blk < 1792) {
    // ---- Mvp[d][256h+c] = sum_dd Wv_c[c,32h+dd]*Wp_c[32h+dd,d]
    int lb = blk - 1280;
    int h = lb >> 6, db = lb & 63;
    float (*wv)[33] = (float(*)[33])smem;
    float (*wp)[33] = (float(*)[33])(smem + 256 * 33);
#pragma unroll
    for (int p = 0; p < 8; p++) {
      int c = (t >> 3) + 32 * p, d4 = (t & 7) * 4;
      float4 v = *(const float4*)(Wv_c + (size_t)c * 256 + 32 * h + d4);
      wv[c][d4 + 0] = v.x; wv[c][d4 + 1] = v.y; wv[c][d4 + 2] = v.z; wv[c][d4 + 3] = v.w;
    }
    if (t < 128) {
      int d_l = t >> 5, dd = t & 31;
      wp[d_l][dd] = Wp_c[(size_t)(32 * h + dd) * 256 + db * 4 + d_l];
    }
    __syncthreads();
    int d_l = t >> 6, ln = t & 63;
    int d = db * 4 + d_l;
#pragma unroll
    for (int j = 0; j < 4; j++) {
      int c = ln + 64 * j;
      float acc = 0.f;
#pragma unroll
      for (int dd = 0; dd < 32; dd++) acc += wv[c][dd] * wp[d_l][dd];
      mvp[(size_t)d * 2048 + 256 * h + c] = f2bf(acc);
    }
  } else if (blk == 1792) {
    // ---- bvp + bqkvs ----
    float acc = bp_c[t];
    for (int dp = 0; dp < 256; dp++) acc += bv_c[dp] * Wp_c[(size_t)dp * 256 + t];
    bvp[t] = acc;
    bqkvs[t] = bq_s[t]; bqkvs[256 + t] = 0.f; bqkvs[512 + t] = bv_s[t];
  } else if (blk < 6017) {
    // ---- LN(pooled) row -> qn_c ----
    int row = blk - 1793, c = t;
    float v = pooled[(size_t)row * C_ + c];
    float s1 = v, s2 = v * v;
#pragma unroll
    for (int m = 32; m > 0; m >>= 1) {
      s1 += __shfl_xor(s1, m, 64); s2 += __shfl_xor(s2, m, 64);
    }
    float* red = smem;
    int wave = c >> 6;
    if ((c & 63) == 0) { red[wave] = s1; red[4 + wave] = s2; }
    __syncthreads();
    s1 = red[0] + red[1] + red[2] + red[3];
    s2 = red[4] + red[5] + red[6] + red[7];
    float mu = s1 * (1.f / C_);
    float rs = rsqrtf(s2 * (1.f / C_) - mu * mu + 1e-5f);
    qn_c[(size_t)row * C_ + c] = f2bf((v - mu) * rs * ln_qc_g[c] + ln_qc_b[c]);
  } else {
    // ---- cross_pe per-row sums: pes[2h]=sum_c pe, pes[2h+1]=sum_c pe^2 ----
    int h = t >> 3, seg = t & 7;
    const float* pr = cross_pe + (size_t)h * 256 + seg * 32;
    float s1 = 0.f, s2 = 0.f;
#pragma unroll
    for (int i = 0; i < 32; i++) { float v = pr[i]; s1 += v; s2 += v * v; }
    s1 += __shfl_xor(s1, 1, 8); s2 += __shfl_xor(s2, 1, 8);
    s1 += __shfl_xor(s1, 2, 8); s2 += __shfl_xor(s2, 2, 8);
    s1 += __shfl_xor(s1, 4, 8); s2 += __shfl_xor(s2, 4, 8);
    if (seg == 0) { pes[2 * h] = s1; pes[2 * h + 1] = s2; }
  }
}

// ---------------------------------------------------------------------------
// cross_fused v5 (resubmit; R7 bench was an infra failure, no data):
// h-split=2. Total parallelism was pinned at 2112 waves (~2/SIMD) in all
// prior versions -- the confirmed latency-bound limiter. Each (b, w-chunk,
// half) block runs the v4 pipelined inner loop over 16 h-steps and writes
// PARTIAL numerator N[hd][c]=accA-accB (f32, 2048) and l[8] to np.
// merge_ctx combines halves. Grid 2112 -> 4224 waves = 4.1/SIMD (the
// VGPR-128 residency cap). Math identical modulo f32 associativity.
// ---------------------------------------------------------------------------
__global__ __launch_bounds__(128, 2) void cross_fused(
    const float* __restrict__ features, const float* __restrict__ cross_pe,
    const unsigned short* __restrict__ qt_g,
    const float* __restrict__ g_kv, const float* __restrict__ b_kv,
    const float* __restrict__ pes,
    float* __restrict__ np) {
  __shared__ __attribute__((aligned(16))) float stage[2 * 4 * 268];
  const int p = blockIdx.x;
  const int xcd = p & 7, slot = p >> 3;       // slot 0..263
  const int b = xcd + 8 * (slot / 44);        // 44 blocks per b, one XCD
  const int rr = slot % 44;
  const int half = rr / 22;
  const int w0 = (rr % 22) * 4;
  const int h0 = half << 4;                   // 0 or 16
  const int t = threadIdx.x;                  // 0..127
  const int bw0 = b * 88 + w0;
  const int w = t >> 5, c8 = t & 31, cbase = c8 << 3;

  // ---- one-time: qg = q*gk in registers; Qg = sum q*gk; Qb = sum q*bk ----
  float qg[8][8], Qg[8], Qb[8];
  {
    float gk8[8], bk8[8];
    float4 u0 = *(const float4*)(g_kv + cbase), u1 = *(const float4*)(g_kv + cbase + 4);
    gk8[0]=u0.x; gk8[1]=u0.y; gk8[2]=u0.z; gk8[3]=u0.w;
    gk8[4]=u1.x; gk8[5]=u1.y; gk8[6]=u1.z; gk8[7]=u1.w;
    u0 = *(const float4*)(b_kv + cbase); u1 = *(const float4*)(b_kv + cbase + 4);
    bk8[0]=u0.x; bk8[1]=u0.y; bk8[2]=u0.z; bk8[3]=u0.w;
    bk8[4]=u1.x; bk8[5]=u1.y; bk8[6]=u1.z; bk8[7]=u1.w;
    const unsigned short* qrow = qt_g + (size_t)(bw0 + w) * 2048 + cbase;
#pragma unroll
    for (int hd = 0; hd < 8; hd++) {
      bf16x8 qv = *(const bf16x8*)(qrow + hd * 256);
      float sg = 0.f, sb = 0.f;
#pragma unroll
      for (int i = 0; i < 8; i++) {
        float qf = (float)qv[i];
        qg[hd][i] = qf * gk8[i];
        sg += qg[hd][i];
        sb += qf * bk8[i];
      }
      Qg[hd] = sg; Qb[hd] = sb;
    }
#pragma unroll
    for (int m = 1; m < 32; m <<= 1) {
#pragma unroll
      for (int hd = 0; hd < 8; hd++) {
        Qg[hd] += __shfl_xor(Qg[hd], m, 32);
        Qb[hd] += __shfl_xor(Qb[hd], m, 32);
      }
    }
  }

  float accA[8][8];
  float accB[8], l[8];
#pragma unroll
  for (int hd = 0; hd < 8; hd++) {
    accB[hd] = 0.f; l[hd] = 0.f;
#pragma unroll
    for (int i = 0; i < 8; i++) accA[hd][i] = 0.f;
  }

  const float* fbase = features + (size_t)b * (C_ * HW_) + w0;  // + c*2816 + h*88
  // loader role: thread t owns rows c = t and c = t+128; one float4 = the 4 w's.
  // 2-deep prologue: X = h0, Y = h0+1.
  float4 x0 = *(const float4*)(fbase + (size_t)t * HW_ + h0 * 88);
  float4 x1 = *(const float4*)(fbase + (size_t)(t + 128) * HW_ + h0 * 88);
  float4 y0 = *(const float4*)(fbase + (size_t)t * HW_ + (h0 + 1) * 88);
  float4 y1 = *(const float4*)(fbase + (size_t)(t + 128) * HW_ + (h0 + 1) * 88);

  // pe row for current step (h0); pes pair for step h0
  float peC[8];
  {
    float4 q0 = *(const float4*)(cross_pe + h0 * 256 + cbase);
    float4 q1 = *(const float4*)(cross_pe + h0 * 256 + cbase + 4);
    peC[0]=q0.x; peC[1]=q0.y; peC[2]=q0.z; peC[3]=q0.w;
    peC[4]=q1.x; peC[5]=q1.y; peC[6]=q1.z; peC[7]=q1.w;
  }
  float pesC1 = pes[2 * h0], pesC2 = pes[2 * h0 + 1];

  // pipeline state: lane-partials + vls of the PREVIOUS h
  float ps1, ps2, pu, pS[8], vprev[8];

  // ---- phase h0 (peeled: dots only, no tree/accumulate yet) ----
  {
    float* st = stage + (h0 & 1) * (4 * 268);
    st[0 * 268 + t] = x0.x; st[1 * 268 + t] = x0.y;
    st[2 * 268 + t] = x0.z; st[3 * 268 + t] = x0.w;
    st[0 * 268 + 128 + t] = x1.x; st[1 * 268 + 128 + t] = x1.y;
    st[2 * 268 + 128 + t] = x1.z; st[3 * 268 + 128 + t] = x1.w;
    asm volatile("s_waitcnt lgkmcnt(0)" ::: "memory");
    __builtin_amdgcn_s_barrier();
    asm volatile("" ::: "memory");
    // prefetch h0+2 into X
    x0 = *(const float4*)(fbase + (size_t)t * HW_ + (h0 + 2) * 88);
    x1 = *(const float4*)(fbase + (size_t)(t + 128) * HW_ + (h0 + 2) * 88);
    const float* sr = st + w * 268 + cbase;
    float4 v0 = *(const float4*)(sr);
    float4 v1 = *(const float4*)(sr + 4);
    float vls[8] = {v0.x, v0.y, v0.z, v0.w, v1.x, v1.y, v1.z, v1.w};
    // prefetch pe for h0+1
    float peN[8];
    {
      float4 q0 = *(const float4*)(cross_pe + (h0 + 1) * 256 + cbase);
      float4 q1 = *(const float4*)(cross_pe + (h0 + 1) * 256 + cbase + 4);
      peN[0]=q0.x; peN[1]=q0.y; peN[2]=q0.z; peN[3]=q0.w;
      peN[4]=q1.x; peN[5]=q1.y; peN[6]=q1.z; peN[7]=q1.w;
    }
    // dots for h0
    float s1 = 0.f, s2 = 0.f, sp = 0.f, vp[8];
#pragma unroll
    for (int i = 0; i < 8; i++) {
      float v = vls[i];
      vp[i] = v + peC[i];
      s1 += v; s2 += v * v; sp += v * peC[i];
    }
#pragma unroll
    for (int hd = 0; hd < 8; hd++) {
      float a = 0.f;
#pragma unroll
      for (int i = 0; i < 8; i++) a += qg[hd][i] * vp[i];
      pS[hd] = a;
    }
    ps1 = s1; ps2 = s2; pu = s2 + 2.f * sp;
#pragma unroll
    for (int i = 0; i < 8; i++) vprev[i] = vls[i];
    // rotate X<->Y, pe  (pesC stays = pes of step h0, consumed next phase)
    float4 t0 = x0, t1 = x1;
    x0 = y0; x1 = y1; y0 = t0; y1 = t1;
#pragma unroll
    for (int i = 0; i < 8; i++) peC[i] = peN[i];
  }

  // ---- phases h = h0+1..h0+15: stage/read/dot(h) || tree/acc(h-1) ----
  for (int h = h0 + 1; h < h0 + 16; ++h) {
    float* st = stage + (h & 1) * (4 * 268);
    st[0 * 268 + t] = x0.x; st[1 * 268 + t] = x0.y;
    st[2 * 268 + t] = x0.z; st[3 * 268 + t] = x0.w;
    st[0 * 268 + 128 + t] = x1.x; st[1 * 268 + 128 + t] = x1.y;
    st[2 * 268 + 128 + t] = x1.z; st[3 * 268 + 128 + t] = x1.w;
    asm volatile("s_waitcnt lgkmcnt(0)" ::: "memory");
    __builtin_amdgcn_s_barrier();
    asm volatile("" ::: "memory");
    if (h + 2 < h0 + 16) {
      x0 = *(const float4*)(fbase + (size_t)t * HW_ + (h + 2) * 88);
      x1 = *(const float4*)(fbase + (size_t)(t + 128) * HW_ + (h + 2) * 88);
    }
    // issue LDS read for step h early
    const float* sr = st + w * 268 + cbase;
    float4 v0 = *(const float4*)(sr);
    float4 v1 = *(const float4*)(sr + 4);
    // ---- TREE for step h-1 (register-only, hides the read + load latency)
#pragma unroll
    for (int m = 1; m < 32; m <<= 1) {
      ps1 += __shfl_xor(ps1, m, 32);
      ps2 += __shfl_xor(ps2, m, 32);
      pu  += __shfl_xor(pu, m, 32);
#pragma unroll
      for (int hd = 0; hd < 8; hd++) pS[hd] += __shfl_xor(pS[hd], m, 32);
    }
    // prefetch pe for h+1
    float peN[8];
    if (h + 1 < h0 + 16) {
      float4 q0 = *(const float4*)(cross_pe + (h + 1) * 256 + cbase);
      float4 q1 = *(const float4*)(cross_pe + (h + 1) * 256 + cbase + 4);
      peN[0]=q0.x; peN[1]=q0.y; peN[2]=q0.z; peN[3]=q0.w;
      peN[4]=q1.x; peN[5]=q1.y; peN[6]=q1.z; peN[7]=q1.w;
    } else {
#pragma unroll
      for (int i = 0; i < 8; i++) peN[i] = 0.f;
    }
    // ---- dots for step h (vls ready by now)
    float vls[8] = {v0.x, v0.y, v0.z, v0.w, v1.x, v1.y, v1.z, v1.w};
    float s1 = 0.f, s2 = 0.f, sp = 0.f, vp[8];
#pragma unroll
    for (int i = 0; i < 8; i++) {
      float v = vls[i];
      vp[i] = v + peC[i];
      s1 += v; s2 += v * v; sp += v * peC[i];
    }
    float nS[8];
#pragma unroll
    for (int hd = 0; hd < 8; hd++) {
      float a = 0.f;
#pragma unroll
      for (int i = 0; i < 8; i++) a += qg[hd][i] * vp[i];
      nS[hd] = a;
    }
    // ---- scalars + softmax accumulate for step h-1 (tree results ready)
    {
      float mu_v = ps1 * (1.f / 256.f);
      float rs_v = rsqrtf(ps2 * (1.f / 256.f) - mu_v * mu_v + 1e-5f);
      float mu_k = (ps1 + pesC1) * (1.f / 256.f);
      float rs_k = rsqrtf((pu + pesC2) * (1.f / 256.f) - mu_k * mu_k + 1e-5f);
#pragma unroll
      for (int hd = 0; hd < 8; hd++) {
        float sc = rs_k * (pS[hd] - mu_k * Qg[hd]) + Qb[hd];
        float e = __expf(sc);
        float er = e * rs_v;
        l[hd] += e;
        accB[hd] += er * mu_v;
#pragma unroll
        for (int i = 0; i < 8; i++) accA[hd][i] += er * vprev[i];
      }
    }
    // ---- rotate pipeline state
    ps1 = s1; ps2 = s2; pu = s2 + 2.f * sp;
#pragma unroll
    for (int hd = 0; hd < 8; hd++) pS[hd] = nS[hd];
#pragma unroll
    for (int i = 0; i < 8; i++) { vprev[i] = vls[i]; peC[i] = peN[i]; }
    pesC1 = pes[2 * h]; pesC2 = pes[2 * h + 1];
    float4 t0 = x0, t1 = x1;
    x0 = y0; x1 = y1; y0 = t0; y1 = t1;
  }

  // ---- epilogue: tree + scalars + accumulate for the last step ----
  {
#pragma unroll
    for (int m = 1; m < 32; m <<= 1) {
      ps1 += __shfl_xor(ps1, m, 32);
      ps2 += __shfl_xor(ps2, m, 32);
      pu  += __shfl_xor(pu, m, 32);
#pragma unroll
      for (int hd = 0; hd < 8; hd++) pS[hd] += __shfl_xor(pS[hd], m, 32);
    }
    float mu_v = ps1 * (1.f / 256.f);
    float rs_v = rsqrtf(ps2 * (1.f / 256.f) - mu_v * mu_v + 1e-5f);
    float mu_k = (ps1 + pesC1) * (1.f / 256.f);
    float rs_k = rsqrtf((pu + pesC2) * (1.f / 256.f) - mu_k * mu_k + 1e-5f);
#pragma unroll
    for (int hd = 0; hd < 8; hd++) {
      float sc = rs_k * (pS[hd] - mu_k * Qg[hd]) + Qb[hd];
      float e = __expf(sc);
      float er = e * rs_v;
      l[hd] += e;
      accB[hd] += er * mu_v;
#pragma unroll
      for (int i = 0; i < 8; i++) accA[hd][i] += er * vprev[i];
    }
  }

  // ---- write partials: N = accA - accB (f32), plus l[8] ----
  float* nrow = np + ((size_t)(bw0 + w) * 2 + half) * NPSTR;
#pragma unroll
  for (int hd = 0; hd < 8; hd++) {
    float4 o0, o1;
    o0.x = accA[hd][0] - accB[hd]; o0.y = accA[hd][1] - accB[hd];
    o0.z = accA[hd][2] - accB[hd]; o0.w = accA[hd][3] - accB[hd];
    o1.x = accA[hd][4] - accB[hd]; o1.y = accA[hd][5] - accB[hd];
    o1.z = accA[hd][6] - accB[hd]; o1.w = accA[hd][7] - accB[hd];
    *(float4*)(nrow + hd * 256 + cbase) = o0;
    *(float4*)(nrow + hd * 256 + cbase + 4) = o1;
  }
  if (c8 == 0) {
#pragma unroll
    for (int hd = 0; hd < 8; hd++) nrow[2048 + hd] = l[hd];
  }
}

// ---------------------------------------------------------------------------
// merge_ctx: ctx[row] = gv*(N0+N1)/(l0+l1) + bv -> bf16. Pure streaming.
// ---------------------------------------------------------------------------
__global__ __launch_bounds__(256) void merge_ctx(
    const float* __restrict__ np, const float* __restrict__ g_vc,
    const float* __restrict__ b_vc, unsigned short* __restrict__ ctx) {
  int row = blockIdx.x, t = threadIdx.x;
  int hd = t >> 5, c0 = (t & 31) << 3;
  const float* n0 = np + (size_t)row * 2 * NPSTR;
  const float* n1 = n0 + NPSTR;
  float inv = 1.f / (n0[2048 + hd] + n1[2048 + hd]);
  float4 a0 = *(const float4*)(n0 + hd * 256 + c0);
  float4 a1 = *(const float4*)(n0 + hd * 256 + c0 + 4);
  float4 b0 = *(const float4*)(n1 + hd * 256 + c0);
  float4 b1 = *(const float4*)(n1 + hd * 256 + c0 + 4);
  float4 g0 = *(const float4*)(g_vc + c0), g1 = *(const float4*)(g_vc + c0 + 4);
  float4 v0 = *(const float4*)(b_vc + c0), v1 = *(const float4*)(b_vc + c0 + 4);
  unsigned short pk[8];
  pk[0] = f2bf(g0.x * (a0.x + b0.x) * inv + v0.x);
  pk[1] = f2bf(g0.y * (a0.y + b0.y) * inv + v0.y);
  pk[2] = f2bf(g0.z * (a0.z + b0.z) * inv + v0.z);
  pk[3] = f2bf(g0.w * (a0.w + b0.w) * inv + v0.w);
  pk[4] = f2bf(g1.x * (a1.x + b1.x) * inv + v1.x);
  pk[5] = f2bf(g1.y * (a1.y + b1.y) * inv + v1.y);
  pk[6] = f2bf(g1.z * (a1.z + b1.z) * inv + v1.z);
  pk[7] = f2bf(g1.w * (a1.w + b1.w) * inv + v1.w);
  *(uint4*)(ctx + (size_t)row * 2048 + hd * 256 + c0) = *(uint4*)pk;
}

// ---------------------------------------------------------------------------
// Row LayerNorm: x f32 [rows, C_] -> bf16 out
// ---------------------------------------------------------------------------
__global__ __launch_bounds__(256) void ln_rows(
    const float* __restrict__ x,
    const float* __restrict__ g, const float* __restrict__ bta,
    unsigned short* __restrict__ out) {
  int row = blockIdx.x, c = threadIdx.x;
  float v = x[(size_t)row * C_ + c];
  float s1 = v, s2 = v * v;
#pragma unroll
  for (int m = 32; m > 0; m >>= 1) {
    s1 += __shfl_xor(s1, m, 64);
    s2 += __shfl_xor(s2, m, 64);
  }
  __shared__ float red[8];
  int wave = c >> 6;
  if ((c & 63) == 0) { red[wave] = s1; red[4 + wave] = s2; }
  __syncthreads();
  s1 = red[0] + red[1] + red[2] + red[3];
  s2 = red[4] + red[5] + red[6] + red[7];
  float mu = s1 * (1.f / C_);
  float rs = rsqrtf(s2 * (1.f / C_) - mu * mu + 1e-5f);
  out[(size_t)row * C_ + c] = f2bf((v - mu) * rs * g[c] + bta[c]);
}

// ---------------------------------------------------------------------------
// ln_dual: out1 = LN(x+pe)*g1+b1, out2 = LN(x)*g2+b2. One read of x.
// ---------------------------------------------------------------------------
__global__ __launch_bounds__(256) void ln_dual(
    const float* __restrict__ x, const float* __restrict__ pe,
    const float* __restrict__ g1, const float* __restrict__ b1a,
    const float* __restrict__ g2, const float* __restrict__ b2a,
    unsigned short* __restrict__ out1, unsigned short* __restrict__ out2) {
  int row = blockIdx.x, c = threadIdx.x;
  float v = x[(size_t)row * C_ + c];
  float vp = v + pe[(size_t)(row % 88) * C_ + c];
  float s1 = v, s2 = v * v, t1 = vp, t2 = vp * vp;
#pragma unroll
  for (int m = 32; m > 0; m >>= 1) {
    s1 += __shfl_xor(s1, m, 64); s2 += __shfl_xor(s2, m, 64);
    t1 += __shfl_xor(t1, m, 64); t2 += __shfl_xor(t2, m, 64);
  }
  __shared__ float red[16];
  int wave = c >> 6;
  if ((c & 63) == 0) {
    red[wave] = s1; red[4 + wave] = s2; red[8 + wave] = t1; red[12 + wave] = t2;
  }
  __syncthreads();
  s1 = red[0] + red[1] + red[2] + red[3];
  s2 = red[4] + red[5] + red[6] + red[7];
  t1 = red[8] + red[9] + red[10] + red[11];
  t2 = red[12] + red[13] + red[14] + red[15];
  float mu = s1 * (1.f / C_), rs = rsqrtf(s2 * (1.f / C_) - mu * mu + 1e-5f);
  float mup = t1 * (1.f / C_), rsp = rsqrtf(t2 * (1.f / C_) - mup * mup + 1e-5f);
  out1[(size_t)row * C_ + c] = f2bf((vp - mup) * rsp * g1[c] + b1a[c]);
  out2[(size_t)row * C_ + c] = f2bf((v - mu) * rs * g2[c] + b2a[c]);
}

// ---------------------------------------------------------------------------
// GEMM: out[M,N] = A[M,K](bf16) @ Bt[N,K](bf16)^T, fp32 acc.
// Register double-buffer: next K-tile loads overlap current MFMA phase.
// ---------------------------------------------------------------------------
__global__ __launch_bounds__(256) void gemm_bt(
    const unsigned short* __restrict__ A, const unsigned short* __restrict__ Bt,
    int M, int N, int K,
    const float* __restrict__ bias, const float* __restrict__ resid,
    float* __restrict__ outF, unsigned short* __restrict__ outB, int act_gelu) {
  __shared__ __attribute__((aligned(16))) unsigned short As[64][32];
  __shared__ __attribute__((aligned(16))) unsigned short Bs[64][32];
  const int tiles_n = N >> 6;
  const int bm = blockIdx.x / tiles_n;
  const int bn = blockIdx.x % tiles_n;
  const int tid = threadIdx.x;
  const int wave = tid >> 6, lane = tid & 63;
  const int quad = lane >> 4, lr = lane & 15;
  const int wm = (wave >> 1) << 5, wn = (wave & 1) << 5;
  const int lrow = tid >> 2;
  const int lcol = (tid & 3) << 3;
  const size_t a_base = (size_t)(bm * 64 + lrow) * K + lcol;
  const size_t b_base = (size_t)(bn * 64 + lrow) * K + lcol;
  f32x4 acc[2][2] = {};
  uint4 areg = *(const uint4*)(A + a_base);
  uint4 breg = *(const uint4*)(Bt + b_base);
  for (int k0 = 0; k0 < K; k0 += 32) {
    *(uint4*)&As[lrow][lcol] = areg;
    *(uint4*)&Bs[lrow][lcol] = breg;
    __syncthreads();
    if (k0 + 32 < K) {
      areg = *(const uint4*)(A + a_base + k0 + 32);
      breg = *(const uint4*)(Bt + b_base + k0 + 32);
    }
    bf16x8 af0 = *(const bf16x8*)&As[wm + lr][quad << 3];
    bf16x8 af1 = *(const bf16x8*)&As[wm + 16 + lr][quad << 3];
    bf16x8 bf0 = *(const bf16x8*)&Bs[wn + lr][quad << 3];
    bf16x8 bf1 = *(const bf16x8*)&Bs[wn + 16 + lr][quad << 3];
    acc[0][0] = __builtin_amdgcn_mfma_f32_16x16x32_bf16(af0, bf0, acc[0][0], 0, 0, 0);
    acc[0][1] = __builtin_amdgcn_mfma_f32_16x16x32_bf16(af0, bf1, acc[0][1], 0, 0, 0);
    acc[1][0] = __builtin_amdgcn_mfma_f32_16x16x32_bf16(af1, bf0, acc[1][0], 0, 0, 0);
    acc[1][1] = __builtin_amdgcn_mfma_f32_16x16x32_bf16(af1, bf1, acc[1][1], 0, 0, 0);
    __syncthreads();
  }
#pragma unroll
  for (int i = 0; i < 2; i++)
#pragma unroll
    for (int j = 0; j < 2; j++)
#pragma unroll
      for (int rr = 0; rr < 4; rr++) {
        int row = bm * 64 + wm + i * 16 + quad * 4 + rr;
        int col = bn * 64 + wn + j * 16 + lr;
        float val = acc[i][j][rr];
        if (bias) val += bias[col];
        if (act_gelu) val = 0.5f * val * (1.f + erff(val * 0.70710678118654752f));
        if (resid) val += resid[(size_t)row * N + col];
        if (outF) outF[(size_t)row * N + col] = val;
        else outB[(size_t)row * N + col] = f2bf(val);
      }
}

// ---------------------------------------------------------------------------
// gemm_bt_st: like gemm_bt but writes f32 with row stride ldc (+bias).
// ---------------------------------------------------------------------------
__global__ __launch_bounds__(256) void gemm_bt_st(
    const unsigned short* __restrict__ A, const unsigned short* __restrict__ Bt,
    int M, int N, int K, int ldc,
    const float* __restrict__ bias, float* __restrict__ outF) {
  __shared__ __attribute__((aligned(16))) unsigned short As[64][32];
  __shared__ __attribute__((aligned(16))) unsigned short Bs[64][32];
  const int tiles_n = N >> 6;
  const int bm = blockIdx.x / tiles_n;
  const int bn = blockIdx.x % tiles_n;
  const int tid = threadIdx.x;
  const int wave = tid >> 6, lane = tid & 63;
  const int quad = lane >> 4, lr = lane & 15;
  const int wm = (wave >> 1) << 5, wn = (wave & 1) << 5;
  const int lrow = tid >> 2;
  const int lcol = (tid & 3) << 3;
  const size_t a_base = (size_t)(bm * 64 + lrow) * K + lcol;
  const size_t b_base = (size_t)(bn * 64 + lrow) * K + lcol;
  f32x4 acc[2][2] = {};
  uint4 areg = *(const uint4*)(A + a_base);
  uint4 breg = *(const uint4*)(Bt + b_base);
  for (int k0 = 0; k0 < K; k0 += 32) {
    *(uint4*)&As[lrow][lcol] = areg;
    *(uint4*)&Bs[lrow][lcol] = breg;
    __syncthreads();
    if (k0 + 32 < K) {
      areg = *(const uint4*)(A + a_base + k0 + 32);
      breg = *(const uint4*)(Bt + b_base + k0 + 32);
    }
    bf16x8 af0 = *(const bf16x8*)&As[wm + lr][quad << 3];
    bf16x8 af1 = *(const bf16x8*)&As[wm + 16 + lr][quad << 3];
    bf16x8 bf0 = *(const bf16x8*)&Bs[wn + lr][quad << 3];
    bf16x8 bf1 = *(const bf16x8*)&Bs[wn + 16 + lr][quad << 3];
    acc[0][0] = __builtin_amdgcn_mfma_f32_16x16x32_bf16(af0, bf0, acc[0][0], 0, 0, 0);
    acc[0][1] = __builtin_amdgcn_mfma_f32_16x16x32_bf16(af0, bf1, acc[0][1], 0, 0, 0);
    acc[1][0] = __builtin_amdgcn_mfma_f32_16x16x32_bf16(af1, bf0, acc[1][0], 0, 0, 0);
    acc[1][1] = __builtin_amdgcn_mfma_f32_16x16x32_bf16(af1, bf1, acc[1][1], 0, 0, 0);
    __syncthreads();
  }
#pragma unroll
  for (int i = 0; i < 2; i++)
#pragma unroll
    for (int j = 0; j < 2; j++)
#pragma unroll
      for (int rr = 0; rr < 4; rr++) {
        int row = bm * 64 + wm + i * 16 + quad * 4 + rr;
        int col = bn * 64 + wn + j * 16 + lr;
        outF[(size_t)row * ldc + col] = acc[i][j][rr] + bias[col];
      }
}

// ---------------------------------------------------------------------------
// self_attn3: block=(b,h), 192 threads: pair (r=t>>1, dh=t&1) per query row.
// qkv f32 [BW_,768] (q+0,k+256,v+512). Scores in registers (44/lane).
// ---------------------------------------------------------------------------
__global__ __launch_bounds__(192) void self_attn3(
    const float* __restrict__ qkv, unsigned short* __restrict__ out) {
  int b = blockIdx.x >> 3;
  int h = blockIdx.x & 7;
  int t = threadIdx.x;
  __shared__ float kl[88][33];
  __shared__ float vl[88][33];
  for (int i = t; i < 704; i += 192) {
    int m = i >> 3, d4 = (i & 7) << 2;
    float4 kv4 = *(const float4*)(qkv + (size_t)(b * 88 + m) * 768 + 256 + h * 32 + d4);
    float4 vv4 = *(const float4*)(qkv + (size_t)(b * 88 + m) * 768 + 512 + h * 32 + d4);
    kl[m][d4 + 0] = kv4.x; kl[m][d4 + 1] = kv4.y; kl[m][d4 + 2] = kv4.z; kl[m][d4 + 3] = kv4.w;
    vl[m][d4 + 0] = vv4.x; vl[m][d4 + 1] = vv4.y; vl[m][d4 + 2] = vv4.z; vl[m][d4 + 3] = vv4.w;
  }
  __syncthreads();
  int r = t >> 1, dh = t & 1;
  if (r < 88) {
    const float* qrow = qkv + (size_t)(b * 88 + r) * 768 + h * 32;
    float qr[32];
#pragma unroll
    for (int g = 0; g < 8; g++) {
      float4 q4 = *(const float4*)(qrow + g * 4);
      qr[g * 4 + 0] = q4.x; qr[g * 4 + 1] = q4.y; qr[g * 4 + 2] = q4.z; qr[g * 4 + 3] = q4.w;
    }
    float sreg[44];
    float mx = -1e30f;
    int m0 = dh * 44;
    for (int mi = 0; mi < 44; mi++) {
      const float* krow = kl[m0 + mi];
      float s = 0.f;
#pragma unroll
      for (int d = 0; d < 32; d++) s += qr[d] * krow[d];
      s *= 0.17677669529663689f;
      sreg[mi] = s;
      mx = fmaxf(mx, s);
    }
    mx = fmaxf(mx, __shfl_xor(mx, 1, 64));
    float sum = 0.f;
    for (int mi = 0; mi < 44; mi++) { float e = __expf(sreg[mi] - mx); sreg[mi] = e; sum += e; }
    sum += __shfl_xor(sum, 1, 64);
    float inv = 1.f / sum;
    float o[32];
#pragma unroll
    for (int d = 0; d < 32; d++) o[d] = 0.f;
    for (int mi = 0; mi < 44; mi++) {
      float p = sreg[mi] * inv;
      const float* vrow = vl[m0 + mi];
#pragma unroll
      for (int d = 0; d < 32; d++) o[d] += p * vrow[d];
    }
#pragma unroll
    for (int d = 0; d < 32; d++) o[d] += __shfl_xor(o[d], 1, 64);
    unsigned short* orow = out + (size_t)(b * 88 + r) * 256 + h * 32 + dh * 16;
    uint4 u0, u1;
    int d0 = dh * 16;
    u0.x = pack2(o[d0 + 0], o[d0 + 1]);  u0.y = pack2(o[d0 + 2], o[d0 + 3]);
    u0.z = pack2(o[d0 + 4], o[d0 + 5]);  u0.w = pack2(o[d0 + 6], o[d0 + 7]);
    u1.x = pack2(o[d0 + 8], o[d0 + 9]);  u1.y = pack2(o[d0 + 10], o[d0 + 11]);
    u1.z = pack2(o[d0 + 12], o[d0 + 13]); u1.w = pack2(o[d0 + 14], o[d0 + 15]);
    *(uint4*)(orow) = u0;
    *(uint4*)(orow + 8) = u1;
  }
}

// ---------------------------------------------------------------------------
extern "C" void kernel_launch(void* const* d_in, const int* in_sizes, int n_in,
                              void* d_out, int out_size, void* d_ws, size_t ws_size,
                              hipStream_t stream) {
  (void)in_sizes; (void)n_in; (void)out_size; (void)ws_size;
  const float* pooled   = (const float*)d_in[0];
  const float* features = (const float*)d_in[1];
  const float* self_pe  = (const float*)d_in[2];
  const float* cross_pe = (const float*)d_in[3];
  const float* ln_qs_g = (const float*)d_in[4],  *ln_qs_b = (const float*)d_in[5];
  const float* ln_vs_g = (const float*)d_in[6],  *ln_vs_b = (const float*)d_in[7];
  const float* ln_qc_g = (const float*)d_in[8],  *ln_qc_b = (const float*)d_in[9];
  const float* ln_kv_g = (const float*)d_in[10], *ln_kv_b = (const float*)d_in[11];
  const float* ln_vc_g = (const float*)d_in[12], *ln_vc_b = (const float*)d_in[13];
  const float* ln_ffn_g = (const float*)d_in[14], *ln_ffn_b = (const float*)d_in[15];
  const float* Wq_s = (const float*)d_in[16], *Wk_s = (const float*)d_in[17];
  const float* Wv_s = (const float*)d_in[18], *Wp_s = (const float*)d_in[19];
  const float* Wq_c = (const float*)d_in[20], *Wk_c = (const float*)d_in[21];
  const float* Wv_c = (const float*)d_in[22], *Wp_c = (const float*)d_in[23];
  const float* bq_s = (const float*)d_in[24], *bv_s = (const float*)d_in[25];
  const float* bp_s = (const float*)d_in[26], *bq_c = (const float*)d_in[27];
  const float* bv_c = (const float*)d_in[28], *bp_c = (const float*)d_in[29];
  const float* W1 = (const float*)d_in[30], *b1 = (const float*)d_in[31];
  const float* W2 = (const float*)d_in[32], *b2 = (const float*)d_in[33];
  float* outp = (float*)d_out;
  char* ws = (char*)d_ws;

  // ---- workspace layout ----
  size_t off = 0;
  auto alloc = [&](size_t bytes) { size_t o = off; off = (off + bytes + 255) & ~(size_t)255; return o; };
  size_t QT  = alloc((size_t)BW_ * 2048 * 2);
  size_t CTX = alloc((size_t)BW_ * 2048 * 2);
  size_t NP  = alloc((size_t)BW_ * 2 * NPSTR * 4);   // 69.7 MB partials
  size_t MQK = alloc((size_t)2048 * 256 * 2);
  size_t MVP = alloc((size_t)256 * 2048 * 2);
  size_t BQK = alloc(2048 * 4);
  size_t BVP = alloc(256 * 4);
  size_t WQKVS = alloc((size_t)768 * 256 * 2);
  size_t BQKVS = alloc(768 * 4);
  size_t WPS = alloc(65536 * 2);
  size_t W1T = alloc(262144 * 2), W2T = alloc(262144 * 2);
  size_t QN_C = alloc((size_t)BW_ * C_ * 2);
  size_t PES  = alloc(64 * 4);
  size_t X1    = alloc((size_t)BW_ * C_ * 4);
  size_t QN_S  = alloc((size_t)BW_ * C_ * 2);
  size_t VN_S  = alloc((size_t)BW_ * C_ * 2);
  size_t QKV_S = alloc((size_t)BW_ * 768 * 4);
  size_t S_O   = alloc((size_t)BW_ * C_ * 2);
  size_t X2    = alloc((size_t)BW_ * C_ * 4);
  size_t FFN   = alloc((size_t)BW_ * C_ * 2);
  size_t H1    = alloc((size_t)BW_ * F_ * 2);

  unsigned short* qt   = (unsigned short*)(ws + QT);
  unsigned short* ctx  = (unsigned short*)(ws + CTX);
  float*          np   = (float*)(ws + NP);
  unsigned short* mqk  = (unsigned short*)(ws + MQK);
  unsigned short* mvp  = (unsigned short*)(ws + MVP);
  float* bqk = (float*)(ws + BQK);
  float* bvp = (float*)(ws + BVP);
  unsigned short* wqkvs = (unsigned short*)(ws + WQKVS);
  float* bqkvs = (float*)(ws + BQKVS);
  unsigned short* wps = (unsigned short*)(ws + WPS);
  unsigned short* w1t = (unsigned short*)(ws + W1T), *w2t = (unsigned short*)(ws + W2T);
  unsigned short* qn_c = (unsigned short*)(ws + QN_C);
  float* pes = (float*)(ws + PES);
  float*          x1   = (float*)(ws + X1);
  unsigned short* qn_s = (unsigned short*)(ws + QN_S);
  unsigned short* vn_s = (unsigned short*)(ws + VN_S);
  float* qkv_s = (float*)(ws + QKV_S);
  unsigned short* s_o  = (unsigned short*)(ws + S_O);
  float*          x2   = (float*)(ws + X2);
  unsigned short* ffn_n = (unsigned short*)(ws + FFN);
  unsigned short* h1    = (unsigned short*)(ws + H1);

  // 1. all prep (weights, folded matrices, LN(pooled), pe sums) in one launch
  prep_all<<<6018, 256, 0, stream>>>(
      Wq_s, Wk_s, Wv_s, Wp_s, W1, W2, Wq_c, Wk_c, Wv_c, Wp_c,
      bq_s, bv_s, bq_c, bv_c, bp_c, pooled, ln_qc_g, ln_qc_b, cross_pe,
      wqkvs, wps, w1t, w2t, mqk, mvp, bqk, bvp, bqkvs, qn_c, pes);

  // 2. q~ = qn_c @ Mqk^T + bqk
  gemm_bt<<<(BW_ / 64) * (2048 / 64), 256, 0, stream>>>(qn_c, mqk, BW_, 2048, 256,
      bqk, nullptr, nullptr, qt, 0);

  // 3. fused LN + cross attention, h-split=2 -> partials
  cross_fused<<<2112, 128, 0, stream>>>(features, cross_pe, qt,
      ln_kv_g, ln_kv_b, pes, np);

  // 3b. merge halves -> ctx (bf16)
  merge_ctx<<<BW_, 256, 0, stream>>>(np, ln_vc_g, ln_vc_b, ctx);

  // 4. x1 = ctx @ Mvp^T + bvp + pooled
  gemm_bt<<<(BW_ / 64) * (C_ / 64), 256, 0, stream>>>(ctx, mvp, BW_, C_, 2048,
      bvp, pooled, x1, nullptr, 0);

  // 5. qn_s = LN(x1+self_pe), vn_s = LN(x1)
  ln_dual<<<BW_, 256, 0, stream>>>(x1, self_pe, ln_qs_g, ln_qs_b,
                                   ln_vs_g, ln_vs_b, qn_s, vn_s);

  // 6. q|k from qn_s -> qkv_s cols [0,512); v from vn_s -> cols [512,768). ldc=768.
  gemm_bt_st<<<(BW_ / 64) * (512 / 64), 256, 0, stream>>>(qn_s, wqkvs, BW_, 512, 256,
      768, bqkvs, qkv_s);
  gemm_bt_st<<<(BW_ / 64) * (256 / 64), 256, 0, stream>>>(vn_s, wqkvs + 131072, BW_, 256, 256,
      768, bqkvs + 512, qkv_s + 512);

  // 7. self attention core
  self_attn3<<<B_ * 8, 192, 0, stream>>>(qkv_s, s_o);

  // 8. x2 = s_o @ Wp_s + bp_s + x1
  gemm_bt<<<(BW_ / 64) * (C_ / 64), 256, 0, stream>>>(s_o, wps, BW_, C_, C_,
      bp_s, x1, x2, nullptr, 0);

  // 9. FFN
  ln_rows<<<BW_, 256, 0, stream>>>(x2, ln_ffn_g, ln_ffn_b, ffn_n);
  gemm_bt<<<(BW_ / 64) * (F_ / 64), 256, 0, stream>>>(ffn_n, w1t, BW_, F_, C_,
      b1, nullptr, nullptr, h1, 1);
  gemm_bt<<<(BW_ / 64) * (C_ / 64), 256, 0, stream>>>(h1, w2t, BW_, C_, F_,
      b2, x2, outp, nullptr, 0);
}

// Round 9
// 489.570 us; speedup vs baseline: 1.1097x; 1.1097x over previous
//
#include <hip/hip_runtime.h>
#include <math.h>

// Problem dims
#define B_   48
#define W_   88
#define C_   256
#define H_   32
#define F_   1024
#define BW_  (B_ * W_)        // 4224
#define BWH_ (B_ * W_ * H_)   // 135168
#define HW_  (H_ * W_)        // 2816

typedef float  f32x4  __attribute__((ext_vector_type(4)));
typedef __bf16 bf16x8 __attribute__((ext_vector_type(8)));

__device__ __forceinline__ unsigned short f2bf(float f) {
  union { float f; unsigned int u; } v; v.f = f;
  unsigned int r = v.u + 0x7FFFu + ((v.u >> 16) & 1u);  // RNE
  return (unsigned short)(r >> 16);
}
__device__ __forceinline__ float bf2f(unsigned short h) {
  union { unsigned int u; float f; } v; v.u = ((unsigned int)h) << 16;
  return v.f;
}
__device__ __forceinline__ unsigned int pack2(float a, float b) {
  return (unsigned int)f2bf(a) | ((unsigned int)f2bf(b) << 16);
}

// DPP butterfly add (VALU pipe, no DS op). Valid butterfly over 32 lanes:
// L1 quad_perm xor1 (0xB1), L2 quad_perm xor2 (0x4E), L3 row_half_mirror
// (0x141; partner in other 4-group, groups already uniform), L4 row_mirror
// (0x140), L5 = xor16 shuffle (cross-row, DS/permlane).
template<int CTRL>
__device__ __forceinline__ float dppadd(float x) {
  union { float f; int i; } a, b;
  a.f = x;
  b.i = __builtin_amdgcn_update_dpp(0, a.i, CTRL, 0xF, 0xF, true);
  return x + b.f;
}

// ---------------------------------------------------------------------------
// prep_all: every weight-prep step in ONE launch.
//  blk [0,768)      : 32x32 LDS tile transposes f32[in,out] -> bf16[out,in]
//  blk [768,1280)   : Mqk build  (512 blocks: h x 64 c-chunks of 4)
//  blk [1280,1792)  : Mvp build  (512 blocks: h x 64 d-chunks of 4)
//  blk 1792         : bvp + bqkvs concat
//  blk [1793,6017)  : LN(pooled) -> qn_c bf16 (one row per block)
//  blk 6017         : cross_pe row sums (pes[2h]=sum, pes[2h+1]=sumsq)
// ---------------------------------------------------------------------------
__global__ __launch_bounds__(256) void prep_all(
    const float* __restrict__ Wq_s, const float* __restrict__ Wk_s,
    const float* __restrict__ Wv_s, const float* __restrict__ Wp_s,
    const float* __restrict__ W1, const float* __restrict__ W2,
    const float* __restrict__ Wq_c, const float* __restrict__ Wk_c,
    const float* __restrict__ Wv_c, const float* __restrict__ Wp_c,
    const float* __restrict__ bq_s, const float* __restrict__ bv_s,
    const float* __restrict__ bq_c, const float* __restrict__ bv_c,
    const float* __restrict__ bp_c,
    const float* __restrict__ pooled,
    const float* __restrict__ ln_qc_g, const float* __restrict__ ln_qc_b,
    const float* __restrict__ cross_pe,
    unsigned short* __restrict__ wqkvs, unsigned short* __restrict__ wps,
    unsigned short* __restrict__ w1t, unsigned short* __restrict__ w2t,
    unsigned short* __restrict__ mqk, unsigned short* __restrict__ mvp,
    float* __restrict__ bqk, float* __restrict__ bvp,
    float* __restrict__ bqkvs, unsigned short* __restrict__ qn_c,
    float* __restrict__ pes) {
  __shared__ float smem[256 * 33 + 4 * 33];
  int blk = blockIdx.x, t = threadIdx.x;

  if (blk < 768) {
    // ---- weight tile transpose ----
    const float* src; unsigned short* dst; int Cc, R, tile;
    if (blk < 64)       { src = Wq_s; dst = wqkvs;          Cc = 256;  R = 256;  tile = blk; }
    else if (blk < 128) { src = Wk_s; dst = wqkvs + 65536;  Cc = 256;  R = 256;  tile = blk - 64; }
    else if (blk < 192) { src = Wv_s; dst = wqkvs + 131072; Cc = 256;  R = 256;  tile = blk - 128; }
    else if (blk < 256) { src = Wp_s; dst = wps;            Cc = 256;  R = 256;  tile = blk - 192; }
    else if (blk < 512) { src = W1;   dst = w1t;            Cc = 1024; R = 256;  tile = blk - 256; }
    else                { src = W2;   dst = w2t;            Cc = 256;  R = 1024; tile = blk - 512; }
    int tcn = Cc >> 5;
    int tr = tile / tcn, tc = tile % tcn;
    float (*lds)[33] = (float(*)[33])smem;
    int r = t >> 3, c4 = (t & 7) * 4;
    float4 v = *(const float4*)(src + (size_t)(tr * 32 + r) * Cc + tc * 32 + c4);
    lds[r][c4 + 0] = v.x; lds[r][c4 + 1] = v.y; lds[r][c4 + 2] = v.z; lds[r][c4 + 3] = v.w;
    __syncthreads();
    // dst[(tc*32+rd)][tr*32 + cd] = src[tr*32+cd][tc*32+rd]
    int rd = t >> 3, cd4 = (t & 7) * 4;
    unsigned int u0 = pack2(lds[cd4 + 0][rd], lds[cd4 + 1][rd]);
    unsigned int u1 = pack2(lds[cd4 + 2][rd], lds[cd4 + 3][rd]);
    uint2 u; u.x = u0; u.y = u1;
    *(uint2*)(dst + (size_t)(tc * 32 + rd) * R + tr * 32 + cd4) = u;
  } else if (blk < 1280) {
    // ---- Mqk[n=256h+c][dp] = scale * sum_dd Wq_c[dp,32h+dd]*Wk_c[c,32h+dd]
    int lb = blk - 768;
    int h = lb >> 6, cb = lb & 63;
    float (*wq)[33] = (float(*)[33])smem;               // [256 dp][32 dd]
    float (*wk)[33] = (float(*)[33])(smem + 256 * 33);  // [4 c][32 dd]
#pragma unroll
    for (int p = 0; p < 8; p++) {
      int dp = (t >> 3) + 32 * p, d4 = (t & 7) * 4;
      float4 v = *(const float4*)(Wq_c + (size_t)dp * 256 + 32 * h + d4);
      wq[dp][d4 + 0] = v.x; wq[dp][d4 + 1] = v.y; wq[dp][d4 + 2] = v.z; wq[dp][d4 + 3] = v.w;
    }
    if (t < 128) {
      int c_l = t >> 5, dd = t & 31;
      wk[c_l][dd] = Wk_c[(size_t)(cb * 4 + c_l) * 256 + 32 * h + dd];
    }
    __syncthreads();
    const float scale = 0.17677669529663689f;
    int c_l = t >> 6, ln = t & 63;
    int n = 256 * h + cb * 4 + c_l;
#pragma unroll
    for (int j = 0; j < 4; j++) {
      int dp = ln + 64 * j;
      float acc = 0.f;
#pragma unroll
      for (int dd = 0; dd < 32; dd++) acc += wq[dp][dd] * wk[c_l][dd];
      mqk[(size_t)n * 256 + dp] = f2bf(acc * scale);
    }
    if (ln == 0) {
      float bb = 0.f;
#pragma unroll
      for (int dd = 0; dd < 32; dd++) bb += bq_c[32 * h + dd] * wk[c_l][dd];
      bqk[n] = bb * scale;
    }
  } else if (blk < 1792) {
    // ---- Mvp[d][256h+c] = sum_dd Wv_c[c,32h+dd]*Wp_c[32h+dd,d]
    int lb = blk - 1280;
    int h = lb >> 6, db = lb & 63;
    float (*wv)[33] = (float(*)[33])smem;
    float (*wp)[33] = (float(*)[33])(smem + 256 * 33);
#pragma unroll
    for (int p = 0; p < 8; p++) {
      int c = (t >> 3) + 32 * p, d4 = (t & 7) * 4;
      float4 v = *(const float4*)(Wv_c + (size_t)c * 256 + 32 * h + d4);
      wv[c][d4 + 0] = v.x; wv[c][d4 + 1] = v.y; wv[c][d4 + 2] = v.z; wv[c][d4 + 3] = v.w;
    }
    if (t < 128) {
      int d_l = t >> 5, dd = t & 31;
      wp[d_l][dd] = Wp_c[(size_t)(32 * h + dd) * 256 + db * 4 + d_l];
    }
    __syncthreads();
    int d_l = t >> 6, ln = t & 63;
    int d = db * 4 + d_l;
#pragma unroll
    for (int j = 0; j < 4; j++) {
      int c = ln + 64 * j;
      float acc = 0.f;
#pragma unroll
      for (int dd = 0; dd < 32; dd++) acc += wv[c][dd] * wp[d_l][dd];
      mvp[(size_t)d * 2048 + 256 * h + c] = f2bf(acc);
    }
  } else if (blk == 1792) {
    // ---- bvp + bqkvs ----
    float acc = bp_c[t];
    for (int dp = 0; dp < 256; dp++) acc += bv_c[dp] * Wp_c[(size_t)dp * 256 + t];
    bvp[t] = acc;
    bqkvs[t] = bq_s[t]; bqkvs[256 + t] = 0.f; bqkvs[512 + t] = bv_s[t];
  } else if (blk < 6017) {
    // ---- LN(pooled) row -> qn_c ----
    int row = blk - 1793, c = t;
    float v = pooled[(size_t)row * C_ + c];
    float s1 = v, s2 = v * v;
#pragma unroll
    for (int m = 32; m > 0; m >>= 1) {
      s1 += __shfl_xor(s1, m, 64); s2 += __shfl_xor(s2, m, 64);
    }
    float* red = smem;
    int wave = c >> 6;
    if ((c & 63) == 0) { red[wave] = s1; red[4 + wave] = s2; }
    __syncthreads();
    s1 = red[0] + red[1] + red[2] + red[3];
    s2 = red[4] + red[5] + red[6] + red[7];
    float mu = s1 * (1.f / C_);
    float rs = rsqrtf(s2 * (1.f / C_) - mu * mu + 1e-5f);
    qn_c[(size_t)row * C_ + c] = f2bf((v - mu) * rs * ln_qc_g[c] + ln_qc_b[c]);
  } else {
    // ---- cross_pe per-row sums: pes[2h]=sum_c pe, pes[2h+1]=sum_c pe^2 ----
    int h = t >> 3, seg = t & 7;
    const float* pr = cross_pe + (size_t)h * 256 + seg * 32;
    float s1 = 0.f, s2 = 0.f;
#pragma unroll
    for (int i = 0; i < 32; i++) { float v = pr[i]; s1 += v; s2 += v * v; }
    s1 += __shfl_xor(s1, 1, 8); s2 += __shfl_xor(s2, 1, 8);
    s1 += __shfl_xor(s1, 2, 8); s2 += __shfl_xor(s2, 2, 8);
    s1 += __shfl_xor(s1, 4, 8); s2 += __shfl_xor(s2, 4, 8);
    if (seg == 0) { pes[2 * h] = s1; pes[2 * h + 1] = s2; }
  }
}

// ---------------------------------------------------------------------------
// cross_fused v6 = v4 (best verified, R6: 131us/500us total) + DPP butterfly.
// R8 showed more waves do NOT help -> the limiter is the per-phase dependent
// chain through the 5-level x 11-value shuffle tree (DS-pipe ops, ~26-40cy
// latency each, shared pipe). v6 moves levels 1-4 to DPP (VALU pipe, ~2-4cy):
// DS ops/thread/phase 55 -> 11, tree critical path ~175 -> ~50 cy.
// Math = same sums reordered (f32, tolerance-safe).
// ---------------------------------------------------------------------------
__global__ __launch_bounds__(128, 2) void cross_fused(
    const float* __restrict__ features, const float* __restrict__ cross_pe,
    const unsigned short* __restrict__ qt_g,
    const float* __restrict__ g_kv, const float* __restrict__ b_kv,
    const float* __restrict__ g_vc, const float* __restrict__ b_vc,
    const float* __restrict__ pes,
    unsigned short* __restrict__ ctx_g) {
  __shared__ __attribute__((aligned(16))) float stage[2 * 4 * 268];
  const int p = blockIdx.x;
  const int xcd = p & 7, slot = p >> 3;       // slot 0..131
  const int b = xcd + 8 * (slot / 22);        // all 22 w-chunks of b on one XCD
  const int w0 = (slot % 22) * 4;
  const int t = threadIdx.x;                  // 0..127
  const int bw0 = b * 88 + w0;
  const int w = t >> 5, c8 = t & 31, cbase = c8 << 3;

  // ---- one-time: qg = q*gk in registers; Qg = sum q*gk; Qb = sum q*bk ----
  float qg[8][8], Qg[8], Qb[8];
  {
    float gk8[8], bk8[8];
    float4 u0 = *(const float4*)(g_kv + cbase), u1 = *(const float4*)(g_kv + cbase + 4);
    gk8[0]=u0.x; gk8[1]=u0.y; gk8[2]=u0.z; gk8[3]=u0.w;
    gk8[4]=u1.x; gk8[5]=u1.y; gk8[6]=u1.z; gk8[7]=u1.w;
    u0 = *(const float4*)(b_kv + cbase); u1 = *(const float4*)(b_kv + cbase + 4);
    bk8[0]=u0.x; bk8[1]=u0.y; bk8[2]=u0.z; bk8[3]=u0.w;
    bk8[4]=u1.x; bk8[5]=u1.y; bk8[6]=u1.z; bk8[7]=u1.w;
    const unsigned short* qrow = qt_g + (size_t)(bw0 + w) * 2048 + cbase;
#pragma unroll
    for (int hd = 0; hd < 8; hd++) {
      bf16x8 qv = *(const bf16x8*)(qrow + hd * 256);
      float sg = 0.f, sb = 0.f;
#pragma unroll
      for (int i = 0; i < 8; i++) {
        float qf = (float)qv[i];
        qg[hd][i] = qf * gk8[i];
        sg += qg[hd][i];
        sb += qf * bk8[i];
      }
      Qg[hd] = sg; Qb[hd] = sb;
    }
#pragma unroll
    for (int m = 1; m < 32; m <<= 1) {
#pragma unroll
      for (int hd = 0; hd < 8; hd++) {
        Qg[hd] += __shfl_xor(Qg[hd], m, 32);
        Qb[hd] += __shfl_xor(Qb[hd], m, 32);
      }
    }
  }

  float accA[8][8];
  float accB[8], l[8];
#pragma unroll
  for (int hd = 0; hd < 8; hd++) {
    accB[hd] = 0.f; l[hd] = 0.f;
#pragma unroll
    for (int i = 0; i < 8; i++) accA[hd][i] = 0.f;
  }

  const float* fbase = features + (size_t)b * (C_ * HW_) + w0;  // + c*2816 + h*88
  // loader role: thread t owns rows c = t and c = t+128; one float4 = the 4 w's.
  // 2-deep prologue: X = h0, Y = h1.
  float4 x0 = *(const float4*)(fbase + (size_t)t * HW_);
  float4 x1 = *(const float4*)(fbase + (size_t)(t + 128) * HW_);
  float4 y0 = *(const float4*)(fbase + (size_t)t * HW_ + 88);
  float4 y1 = *(const float4*)(fbase + (size_t)(t + 128) * HW_ + 88);

  // pe row for current step (h=0); pes pair for step 0
  float peC[8];
  {
    float4 q0 = *(const float4*)(cross_pe + cbase);
    float4 q1 = *(const float4*)(cross_pe + cbase + 4);
    peC[0]=q0.x; peC[1]=q0.y; peC[2]=q0.z; peC[3]=q0.w;
    peC[4]=q1.x; peC[5]=q1.y; peC[6]=q1.z; peC[7]=q1.w;
  }
  float pesC1 = pes[0], pesC2 = pes[1];

  // pipeline state: lane-partials + vls of the PREVIOUS h
  float ps1, ps2, pu, pS[8], vprev[8];

  // ---- phase 0 (peeled: dots only, no tree/accumulate yet) ----
  {
    float* st = stage;
    st[0 * 268 + t] = x0.x; st[1 * 268 + t] = x0.y;
    st[2 * 268 + t] = x0.z; st[3 * 268 + t] = x0.w;
    st[0 * 268 + 128 + t] = x1.x; st[1 * 268 + 128 + t] = x1.y;
    st[2 * 268 + 128 + t] = x1.z; st[3 * 268 + 128 + t] = x1.w;
    asm volatile("s_waitcnt lgkmcnt(0)" ::: "memory");
    __builtin_amdgcn_s_barrier();
    asm volatile("" ::: "memory");
    // prefetch h=2 into X
    x0 = *(const float4*)(fbase + (size_t)t * HW_ + 2 * 88);
    x1 = *(const float4*)(fbase + (size_t)(t + 128) * HW_ + 2 * 88);
    const float* sr = st + w * 268 + cbase;
    float4 v0 = *(const float4*)(sr);
    float4 v1 = *(const float4*)(sr + 4);
    float vls[8] = {v0.x, v0.y, v0.z, v0.w, v1.x, v1.y, v1.z, v1.w};
    // prefetch pe for h=1
    float peN[8];
    {
      float4 q0 = *(const float4*)(cross_pe + 256 + cbase);
      float4 q1 = *(const float4*)(cross_pe + 256 + cbase + 4);
      peN[0]=q0.x; peN[1]=q0.y; peN[2]=q0.z; peN[3]=q0.w;
      peN[4]=q1.x; peN[5]=q1.y; peN[6]=q1.z; peN[7]=q1.w;
    }
    // dots for h=0
    float s1 = 0.f, s2 = 0.f, sp = 0.f, vp[8];
#pragma unroll
    for (int i = 0; i < 8; i++) {
      float v = vls[i];
      vp[i] = v + peC[i];
      s1 += v; s2 += v * v; sp += v * peC[i];
    }
#pragma unroll
    for (int hd = 0; hd < 8; hd++) {
      float a = 0.f;
#pragma unroll
      for (int i = 0; i < 8; i++) a += qg[hd][i] * vp[i];
      pS[hd] = a;
    }
    ps1 = s1; ps2 = s2; pu = s2 + 2.f * sp;
#pragma unroll
    for (int i = 0; i < 8; i++) vprev[i] = vls[i];
    // rotate X<->Y, pe  (pesC stays = pes of step 0, consumed in phase 1)
    float4 t0 = x0, t1 = x1;
    x0 = y0; x1 = y1; y0 = t0; y1 = t1;
#pragma unroll
    for (int i = 0; i < 8; i++) peC[i] = peN[i];
  }

  // ---- phases h = 1..31: stage/read/dot(h) overlapped with tree/acc(h-1) ----
  for (int h = 1; h < 32; ++h) {
    float* st = stage + (h & 1) * (4 * 268);
    st[0 * 268 + t] = x0.x; st[1 * 268 + t] = x0.y;
    st[2 * 268 + t] = x0.z; st[3 * 268 + t] = x0.w;
    st[0 * 268 + 128 + t] = x1.x; st[1 * 268 + 128 + t] = x1.y;
    st[2 * 268 + 128 + t] = x1.z; st[3 * 268 + 128 + t] = x1.w;
    asm volatile("s_waitcnt lgkmcnt(0)" ::: "memory");
    __builtin_amdgcn_s_barrier();
    asm volatile("" ::: "memory");
    if (h < 30) {
      x0 = *(const float4*)(fbase + (size_t)t * HW_ + (h + 2) * 88);
      x1 = *(const float4*)(fbase + (size_t)(t + 128) * HW_ + (h + 2) * 88);
    }
    // issue LDS read for step h early
    const float* sr = st + w * 268 + cbase;
    float4 v0 = *(const float4*)(sr);
    float4 v1 = *(const float4*)(sr + 4);
    // ---- TREE for step h-1: levels 1-4 on DPP (VALU), level 16 via shuffle
    // L1 xor1
    ps1 = dppadd<0xB1>(ps1); ps2 = dppadd<0xB1>(ps2); pu = dppadd<0xB1>(pu);
#pragma unroll
    for (int hd = 0; hd < 8; hd++) pS[hd] = dppadd<0xB1>(pS[hd]);
    // L2 xor2
    ps1 = dppadd<0x4E>(ps1); ps2 = dppadd<0x4E>(ps2); pu = dppadd<0x4E>(pu);
#pragma unroll
    for (int hd = 0; hd < 8; hd++) pS[hd] = dppadd<0x4E>(pS[hd]);
    // L3 row_half_mirror (butterfly across 4-groups)
    ps1 = dppadd<0x141>(ps1); ps2 = dppadd<0x141>(ps2); pu = dppadd<0x141>(pu);
#pragma unroll
    for (int hd = 0; hd < 8; hd++) pS[hd] = dppadd<0x141>(pS[hd]);
    // L4 row_mirror (across 8-groups)
    ps1 = dppadd<0x140>(ps1); ps2 = dppadd<0x140>(ps2); pu = dppadd<0x140>(pu);
#pragma unroll
    for (int hd = 0; hd < 8; hd++) pS[hd] = dppadd<0x140>(pS[hd]);
    // L5 xor16
    ps1 += __shfl_xor(ps1, 16, 32);
    ps2 += __shfl_xor(ps2, 16, 32);
    pu  += __shfl_xor(pu, 16, 32);
#pragma unroll
    for (int hd = 0; hd < 8; hd++) pS[hd] += __shfl_xor(pS[hd], 16, 32);
    // prefetch pe for h+1
    float peN[8];
    if (h < 31) {
      float4 q0 = *(const float4*)(cross_pe + (h + 1) * 256 + cbase);
      float4 q1 = *(const float4*)(cross_pe + (h + 1) * 256 + cbase + 4);
      peN[0]=q0.x; peN[1]=q0.y; peN[2]=q0.z; peN[3]=q0.w;
      peN[4]=q1.x; peN[5]=q1.y; peN[6]=q1.z; peN[7]=q1.w;
    } else {
#pragma unroll
      for (int i = 0; i < 8; i++) peN[i] = 0.f;
    }
    // ---- dots for step h (vls ready by now)
    float vls[8] = {v0.x, v0.y, v0.z, v0.w, v1.x, v1.y, v1.z, v1.w};
    float s1 = 0.f, s2 = 0.f, sp = 0.f, vp[8];
#pragma unroll
    for (int i = 0; i < 8; i++) {
      float v = vls[i];
      vp[i] = v + peC[i];
      s1 += v; s2 += v * v; sp += v * peC[i];
    }
    float nS[8];
#pragma unroll
    for (int hd = 0; hd < 8; hd++) {
      float a = 0.f;
#pragma unroll
      for (int i = 0; i < 8; i++) a += qg[hd][i] * vp[i];
      nS[hd] = a;
    }
    // ---- scalars + softmax accumulate for step h-1 (tree results ready)
    {
      float mu_v = ps1 * (1.f / 256.f);
      float rs_v = rsqrtf(ps2 * (1.f / 256.f) - mu_v * mu_v + 1e-5f);
      float mu_k = (ps1 + pesC1) * (1.f / 256.f);
      float rs_k = rsqrtf((pu + pesC2) * (1.f / 256.f) - mu_k * mu_k + 1e-5f);
#pragma unroll
      for (int hd = 0; hd < 8; hd++) {
        float sc = rs_k * (pS[hd] - mu_k * Qg[hd]) + Qb[hd];
        float e = __expf(sc);
        float er = e * rs_v;
        l[hd] += e;
        accB[hd] += er * mu_v;
#pragma unroll
        for (int i = 0; i < 8; i++) accA[hd][i] += er * vprev[i];
      }
    }
    // ---- rotate pipeline state
    ps1 = s1; ps2 = s2; pu = s2 + 2.f * sp;
#pragma unroll
    for (int hd = 0; hd < 8; hd++) pS[hd] = nS[hd];
#pragma unroll
    for (int i = 0; i < 8; i++) { vprev[i] = vls[i]; peC[i] = peN[i]; }
    pesC1 = pes[2 * h]; pesC2 = pes[2 * h + 1];
    float4 t0 = x0, t1 = x1;
    x0 = y0; x1 = y1; y0 = t0; y1 = t1;
  }

  // ---- epilogue: tree + scalars + accumulate for h=31 ----
  {
    ps1 = dppadd<0xB1>(ps1); ps2 = dppadd<0xB1>(ps2); pu = dppadd<0xB1>(pu);
#pragma unroll
    for (int hd = 0; hd < 8; hd++) pS[hd] = dppadd<0xB1>(pS[hd]);
    ps1 = dppadd<0x4E>(ps1); ps2 = dppadd<0x4E>(ps2); pu = dppadd<0x4E>(pu);
#pragma unroll
    for (int hd = 0; hd < 8; hd++) pS[hd] = dppadd<0x4E>(pS[hd]);
    ps1 = dppadd<0x141>(ps1); ps2 = dppadd<0x141>(ps2); pu = dppadd<0x141>(pu);
#pragma unroll
    for (int hd = 0; hd < 8; hd++) pS[hd] = dppadd<0x141>(pS[hd]);
    ps1 = dppadd<0x140>(ps1); ps2 = dppadd<0x140>(ps2); pu = dppadd<0x140>(pu);
#pragma unroll
    for (int hd = 0; hd < 8; hd++) pS[hd] = dppadd<0x140>(pS[hd]);
    ps1 += __shfl_xor(ps1, 16, 32);
    ps2 += __shfl_xor(ps2, 16, 32);
    pu  += __shfl_xor(pu, 16, 32);
#pragma unroll
    for (int hd = 0; hd < 8; hd++) pS[hd] += __shfl_xor(pS[hd], 16, 32);
    float mu_v = ps1 * (1.f / 256.f);
    float rs_v = rsqrtf(ps2 * (1.f / 256.f) - mu_v * mu_v + 1e-5f);
    float mu_k = (ps1 + pesC1) * (1.f / 256.f);
    float rs_k = rsqrtf((pu + pesC2) * (1.f / 256.f) - mu_k * mu_k + 1e-5f);
#pragma unroll
    for (int hd = 0; hd < 8; hd++) {
      float sc = rs_k * (pS[hd] - mu_k * Qg[hd]) + Qb[hd];
      float e = __expf(sc);
      float er = e * rs_v;
      l[hd] += e;
      accB[hd] += er * mu_v;
#pragma unroll
      for (int i = 0; i < 8; i++) accA[hd][i] += er * vprev[i];
    }
  }

  // epilogue: ctx = gv*(accA-accB)/l + bv -> bf16
  float gv8[8], bv8[8];
  {
    float4 u0 = *(const float4*)(g_vc + cbase), u1 = *(const float4*)(g_vc + cbase + 4);
    gv8[0]=u0.x; gv8[1]=u0.y; gv8[2]=u0.z; gv8[3]=u0.w;
    gv8[4]=u1.x; gv8[5]=u1.y; gv8[6]=u1.z; gv8[7]=u1.w;
    u0 = *(const float4*)(b_vc + cbase); u1 = *(const float4*)(b_vc + cbase + 4);
    bv8[0]=u0.x; bv8[1]=u0.y; bv8[2]=u0.z; bv8[3]=u0.w;
    bv8[4]=u1.x; bv8[5]=u1.y; bv8[6]=u1.z; bv8[7]=u1.w;
  }
  unsigned short* orow = ctx_g + (size_t)(bw0 + w) * 2048 + cbase;
#pragma unroll
  for (int hd = 0; hd < 8; hd++) {
    float inv = 1.f / l[hd];
    unsigned short pk[8];
#pragma unroll
    for (int i = 0; i < 8; i++)
      pk[i] = f2bf(gv8[i] * (accA[hd][i] - accB[hd]) * inv + bv8[i]);
    *(uint4*)(orow + hd * 256) = *(uint4*)pk;
  }
}

// ---------------------------------------------------------------------------
// Row LayerNorm: x f32 [rows, C_] -> bf16 out
// ---------------------------------------------------------------------------
__global__ __launch_bounds__(256) void ln_rows(
    const float* __restrict__ x,
    const float* __restrict__ g, const float* __restrict__ bta,
    unsigned short* __restrict__ out) {
  int row = blockIdx.x, c = threadIdx.x;
  float v = x[(size_t)row * C_ + c];
  float s1 = v, s2 = v * v;
#pragma unroll
  for (int m = 32; m > 0; m >>= 1) {
    s1 += __shfl_xor(s1, m, 64);
    s2 += __shfl_xor(s2, m, 64);
  }
  __shared__ float red[8];
  int wave = c >> 6;
  if ((c & 63) == 0) { red[wave] = s1; red[4 + wave] = s2; }
  __syncthreads();
  s1 = red[0] + red[1] + red[2] + red[3];
  s2 = red[4] + red[5] + red[6] + red[7];
  float mu = s1 * (1.f / C_);
  float rs = rsqrtf(s2 * (1.f / C_) - mu * mu + 1e-5f);
  out[(size_t)row * C_ + c] = f2bf((v - mu) * rs * g[c] + bta[c]);
}

// ---------------------------------------------------------------------------
// ln_dual: out1 = LN(x+pe)*g1+b1, out2 = LN(x)*g2+b2. One read of x.
// ---------------------------------------------------------------------------
__global__ __launch_bounds__(256) void ln_dual(
    const float* __restrict__ x, const float* __restrict__ pe,
    const float* __restrict__ g1, const float* __restrict__ b1a,
    const float* __restrict__ g2, const float* __restrict__ b2a,
    unsigned short* __restrict__ out1, unsigned short* __restrict__ out2) {
  int row = blockIdx.x, c = threadIdx.x;
  float v = x[(size_t)row * C_ + c];
  float vp = v + pe[(size_t)(row % 88) * C_ + c];
  float s1 = v, s2 = v * v, t1 = vp, t2 = vp * vp;
#pragma unroll
  for (int m = 32; m > 0; m >>= 1) {
    s1 += __shfl_xor(s1, m, 64); s2 += __shfl_xor(s2, m, 64);
    t1 += __shfl_xor(t1, m, 64); t2 += __shfl_xor(t2, m, 64);
  }
  __shared__ float red[16];
  int wave = c >> 6;
  if ((c & 63) == 0) {
    red[wave] = s1; red[4 + wave] = s2; red[8 + wave] = t1; red[12 + wave] = t2;
  }
  __syncthreads();
  s1 = red[0] + red[1] + red[2] + red[3];
  s2 = red[4] + red[5] + red[6] + red[7];
  t1 = red[8] + red[9] + red[10] + red[11];
  t2 = red[12] + red[13] + red[14] + red[15];
  float mu = s1 * (1.f / C_), rs = rsqrtf(s2 * (1.f / C_) - mu * mu + 1e-5f);
  float mup = t1 * (1.f / C_), rsp = rsqrtf(t2 * (1.f / C_) - mup * mup + 1e-5f);
  out1[(size_t)row * C_ + c] = f2bf((vp - mup) * rsp * g1[c] + b1a[c]);
  out2[(size_t)row * C_ + c] = f2bf((v - mu) * rs * g2[c] + b2a[c]);
}

// ---------------------------------------------------------------------------
// GEMM: out[M,N] = A[M,K](bf16) @ Bt[N,K](bf16)^T, fp32 acc.
// Register double-buffer: next K-tile loads overlap current MFMA phase.
// ---------------------------------------------------------------------------
__global__ __launch_bounds__(256) void gemm_bt(
    const unsigned short* __restrict__ A, const unsigned short* __restrict__ Bt,
    int M, int N, int K,
    const float* __restrict__ bias, const float* __restrict__ resid,
    float* __restrict__ outF, unsigned short* __restrict__ outB, int act_gelu) {
  __shared__ __attribute__((aligned(16))) unsigned short As[64][32];
  __shared__ __attribute__((aligned(16))) unsigned short Bs[64][32];
  const int tiles_n = N >> 6;
  const int bm = blockIdx.x / tiles_n;
  const int bn = blockIdx.x % tiles_n;
  const int tid = threadIdx.x;
  const int wave = tid >> 6, lane = tid & 63;
  const int quad = lane >> 4, lr = lane & 15;
  const int wm = (wave >> 1) << 5, wn = (wave & 1) << 5;
  const int lrow = tid >> 2;
  const int lcol = (tid & 3) << 3;
  const size_t a_base = (size_t)(bm * 64 + lrow) * K + lcol;
  const size_t b_base = (size_t)(bn * 64 + lrow) * K + lcol;
  f32x4 acc[2][2] = {};
  uint4 areg = *(const uint4*)(A + a_base);
  uint4 breg = *(const uint4*)(Bt + b_base);
  for (int k0 = 0; k0 < K; k0 += 32) {
    *(uint4*)&As[lrow][lcol] = areg;
    *(uint4*)&Bs[lrow][lcol] = breg;
    __syncthreads();
    if (k0 + 32 < K) {
      areg = *(const uint4*)(A + a_base + k0 + 32);
      breg = *(const uint4*)(Bt + b_base + k0 + 32);
    }
    bf16x8 af0 = *(const bf16x8*)&As[wm + lr][quad << 3];
    bf16x8 af1 = *(const bf16x8*)&As[wm + 16 + lr][quad << 3];
    bf16x8 bf0 = *(const bf16x8*)&Bs[wn + lr][quad << 3];
    bf16x8 bf1 = *(const bf16x8*)&Bs[wn + 16 + lr][quad << 3];
    acc[0][0] = __builtin_amdgcn_mfma_f32_16x16x32_bf16(af0, bf0, acc[0][0], 0, 0, 0);
    acc[0][1] = __builtin_amdgcn_mfma_f32_16x16x32_bf16(af0, bf1, acc[0][1], 0, 0, 0);
    acc[1][0] = __builtin_amdgcn_mfma_f32_16x16x32_bf16(af1, bf0, acc[1][0], 0, 0, 0);
    acc[1][1] = __builtin_amdgcn_mfma_f32_16x16x32_bf16(af1, bf1, acc[1][1], 0, 0, 0);
    __syncthreads();
  }
#pragma unroll
  for (int i = 0; i < 2; i++)
#pragma unroll
    for (int j = 0; j < 2; j++)
#pragma unroll
      for (int rr = 0; rr < 4; rr++) {
        int row = bm * 64 + wm + i * 16 + quad * 4 + rr;
        int col = bn * 64 + wn + j * 16 + lr;
        float val = acc[i][j][rr];
        if (bias) val += bias[col];
        if (act_gelu) val = 0.5f * val * (1.f + erff(val * 0.70710678118654752f));
        if (resid) val += resid[(size_t)row * N + col];
        if (outF) outF[(size_t)row * N + col] = val;
        else outB[(size_t)row * N + col] = f2bf(val);
      }
}

// ---------------------------------------------------------------------------
// gemm_bt_st: like gemm_bt but writes f32 with row stride ldc (+bias).
// ---------------------------------------------------------------------------
__global__ __launch_bounds__(256) void gemm_bt_st(
    const unsigned short* __restrict__ A, const unsigned short* __restrict__ Bt,
    int M, int N, int K, int ldc,
    const float* __restrict__ bias, float* __restrict__ outF) {
  __shared__ __attribute__((aligned(16))) unsigned short As[64][32];
  __shared__ __attribute__((aligned(16))) unsigned short Bs[64][32];
  const int tiles_n = N >> 6;
  const int bm = blockIdx.x / tiles_n;
  const int bn = blockIdx.x % tiles_n;
  const int tid = threadIdx.x;
  const int wave = tid >> 6, lane = tid & 63;
  const int quad = lane >> 4, lr = lane & 15;
  const int wm = (wave >> 1) << 5, wn = (wave & 1) << 5;
  const int lrow = tid >> 2;
  const int lcol = (tid & 3) << 3;
  const size_t a_base = (size_t)(bm * 64 + lrow) * K + lcol;
  const size_t b_base = (size_t)(bn * 64 + lrow) * K + lcol;
  f32x4 acc[2][2] = {};
  uint4 areg = *(const uint4*)(A + a_base);
  uint4 breg = *(const uint4*)(Bt + b_base);
  for (int k0 = 0; k0 < K; k0 += 32) {
    *(uint4*)&As[lrow][lcol] = areg;
    *(uint4*)&Bs[lrow][lcol] = breg;
    __syncthreads();
    if (k0 + 32 < K) {
      areg = *(const uint4*)(A + a_base + k0 + 32);
      breg = *(const uint4*)(Bt + b_base + k0 + 32);
    }
    bf16x8 af0 = *(const bf16x8*)&As[wm + lr][quad << 3];
    bf16x8 af1 = *(const bf16x8*)&As[wm + 16 + lr][quad << 3];
    bf16x8 bf0 = *(const bf16x8*)&Bs[wn + lr][quad << 3];
    bf16x8 bf1 = *(const bf16x8*)&Bs[wn + 16 + lr][quad << 3];
    acc[0][0] = __builtin_amdgcn_mfma_f32_16x16x32_bf16(af0, bf0, acc[0][0], 0, 0, 0);
    acc[0][1] = __builtin_amdgcn_mfma_f32_16x16x32_bf16(af0, bf1, acc[0][1], 0, 0, 0);
    acc[1][0] = __builtin_amdgcn_mfma_f32_16x16x32_bf16(af1, bf0, acc[1][0], 0, 0, 0);
    acc[1][1] = __builtin_amdgcn_mfma_f32_16x16x32_bf16(af1, bf1, acc[1][1], 0, 0, 0);
    __syncthreads();
  }
#pragma unroll
  for (int i = 0; i < 2; i++)
#pragma unroll
    for (int j = 0; j < 2; j++)
#pragma unroll
      for (int rr = 0; rr < 4; rr++) {
        int row = bm * 64 + wm + i * 16 + quad * 4 + rr;
        int col = bn * 64 + wn + j * 16 + lr;
        outF[(size_t)row * ldc + col] = acc[i][j][rr] + bias[col];
      }
}

// ---------------------------------------------------------------------------
// self_attn3: block=(b,h), 192 threads: pair (r=t>>1, dh=t&1) per query row.
// qkv f32 [BW_,768] (q+0,k+256,v+512). Scores in registers (44/lane).
// ---------------------------------------------------------------------------
__global__ __launch_bounds__(192) void self_attn3(
    const float* __restrict__ qkv, unsigned short* __restrict__ out) {
  int b = blockIdx.x >> 3;
  int h = blockIdx.x & 7;
  int t = threadIdx.x;
  __shared__ float kl[88][33];
  __shared__ float vl[88][33];
  for (int i = t; i < 704; i += 192) {
    int m = i >> 3, d4 = (i & 7) << 2;
    float4 kv4 = *(const float4*)(qkv + (size_t)(b * 88 + m) * 768 + 256 + h * 32 + d4);
    float4 vv4 = *(const float4*)(qkv + (size_t)(b * 88 + m) * 768 + 512 + h * 32 + d4);
    kl[m][d4 + 0] = kv4.x; kl[m][d4 + 1] = kv4.y; kl[m][d4 + 2] = kv4.z; kl[m][d4 + 3] = kv4.w;
    vl[m][d4 + 0] = vv4.x; vl[m][d4 + 1] = vv4.y; vl[m][d4 + 2] = vv4.z; vl[m][d4 + 3] = vv4.w;
  }
  __syncthreads();
  int r = t >> 1, dh = t & 1;
  if (r < 88) {
    const float* qrow = qkv + (size_t)(b * 88 + r) * 768 + h * 32;
    float qr[32];
#pragma unroll
    for (int g = 0; g < 8; g++) {
      float4 q4 = *(const float4*)(qrow + g * 4);
      qr[g * 4 + 0] = q4.x; qr[g * 4 + 1] = q4.y; qr[g * 4 + 2] = q4.z; qr[g * 4 + 3] = q4.w;
    }
    float sreg[44];
    float mx = -1e30f;
    int m0 = dh * 44;
    for (int mi = 0; mi < 44; mi++) {
      const float* krow = kl[m0 + mi];
      float s = 0.f;
#pragma unroll
      for (int d = 0; d < 32; d++) s += qr[d] * krow[d];
      s *= 0.17677669529663689f;
      sreg[mi] = s;
      mx = fmaxf(mx, s);
    }
    mx = fmaxf(mx, __shfl_xor(mx, 1, 64));
    float sum = 0.f;
    for (int mi = 0; mi < 44; mi++) { float e = __expf(sreg[mi] - mx); sreg[mi] = e; sum += e; }
    sum += __shfl_xor(sum, 1, 64);
    float inv = 1.f / sum;
    float o[32];
#pragma unroll
    for (int d = 0; d < 32; d++) o[d] = 0.f;
    for (int mi = 0; mi < 44; mi++) {
      float p = sreg[mi] * inv;
      const float* vrow = vl[m0 + mi];
#pragma unroll
      for (int d = 0; d < 32; d++) o[d] += p * vrow[d];
    }
#pragma unroll
    for (int d = 0; d < 32; d++) o[d] += __shfl_xor(o[d], 1, 64);
    unsigned short* orow = out + (size_t)(b * 88 + r) * 256 + h * 32 + dh * 16;
    uint4 u0, u1;
    int d0 = dh * 16;
    u0.x = pack2(o[d0 + 0], o[d0 + 1]);  u0.y = pack2(o[d0 + 2], o[d0 + 3]);
    u0.z = pack2(o[d0 + 4], o[d0 + 5]);  u0.w = pack2(o[d0 + 6], o[d0 + 7]);
    u1.x = pack2(o[d0 + 8], o[d0 + 9]);  u1.y = pack2(o[d0 + 10], o[d0 + 11]);
    u1.z = pack2(o[d0 + 12], o[d0 + 13]); u1.w = pack2(o[d0 + 14], o[d0 + 15]);
    *(uint4*)(orow) = u0;
    *(uint4*)(orow + 8) = u1;
  }
}

// ---------------------------------------------------------------------------
extern "C" void kernel_launch(void* const* d_in, const int* in_sizes, int n_in,
                              void* d_out, int out_size, void* d_ws, size_t ws_size,
                              hipStream_t stream) {
  (void)in_sizes; (void)n_in; (void)out_size; (void)ws_size;
  const float* pooled   = (const float*)d_in[0];
  const float* features = (const float*)d_in[1];
  const float* self_pe  = (const float*)d_in[2];
  const float* cross_pe = (const float*)d_in[3];
  const float* ln_qs_g = (const float*)d_in[4],  *ln_qs_b = (const float*)d_in[5];
  const float* ln_vs_g = (const float*)d_in[6],  *ln_vs_b = (const float*)d_in[7];
  const float* ln_qc_g = (const float*)d_in[8],  *ln_qc_b = (const float*)d_in[9];
  const float* ln_kv_g = (const float*)d_in[10], *ln_kv_b = (const float*)d_in[11];
  const float* ln_vc_g = (const float*)d_in[12], *ln_vc_b = (const float*)d_in[13];
  const float* ln_ffn_g = (const float*)d_in[14], *ln_ffn_b = (const float*)d_in[15];
  const float* Wq_s = (const float*)d_in[16], *Wk_s = (const float*)d_in[17];
  const float* Wv_s = (const float*)d_in[18], *Wp_s = (const float*)d_in[19];
  const float* Wq_c = (const float*)d_in[20], *Wk_c = (const float*)d_in[21];
  const float* Wv_c = (const float*)d_in[22], *Wp_c = (const float*)d_in[23];
  const float* bq_s = (const float*)d_in[24], *bv_s = (const float*)d_in[25];
  const float* bp_s = (const float*)d_in[26], *bq_c = (const float*)d_in[27];
  const float* bv_c = (const float*)d_in[28], *bp_c = (const float*)d_in[29];
  const float* W1 = (const float*)d_in[30], *b1 = (const float*)d_in[31];
  const float* W2 = (const float*)d_in[32], *b2 = (const float*)d_in[33];
  float* outp = (float*)d_out;
  char* ws = (char*)d_ws;

  // ---- workspace layout ----
  size_t off = 0;
  auto alloc = [&](size_t bytes) { size_t o = off; off = (off + bytes + 255) & ~(size_t)255; return o; };
  size_t QT  = alloc((size_t)BW_ * 2048 * 2);
  size_t CTX = alloc((size_t)BW_ * 2048 * 2);
  size_t MQK = alloc((size_t)2048 * 256 * 2);
  size_t MVP = alloc((size_t)256 * 2048 * 2);
  size_t BQK = alloc(2048 * 4);
  size_t BVP = alloc(256 * 4);
  size_t WQKVS = alloc((size_t)768 * 256 * 2);
  size_t BQKVS = alloc(768 * 4);
  size_t WPS = alloc(65536 * 2);
  size_t W1T = alloc(262144 * 2), W2T = alloc(262144 * 2);
  size_t QN_C = alloc((size_t)BW_ * C_ * 2);
  size_t PES  = alloc(64 * 4);
  size_t X1    = alloc((size_t)BW_ * C_ * 4);
  size_t QN_S  = alloc((size_t)BW_ * C_ * 2);
  size_t VN_S  = alloc((size_t)BW_ * C_ * 2);
  size_t QKV_S = alloc((size_t)BW_ * 768 * 4);
  size_t S_O   = alloc((size_t)BW_ * C_ * 2);
  size_t X2    = alloc((size_t)BW_ * C_ * 4);
  size_t FFN   = alloc((size_t)BW_ * C_ * 2);
  size_t H1    = alloc((size_t)BW_ * F_ * 2);

  unsigned short* qt   = (unsigned short*)(ws + QT);
  unsigned short* ctx  = (unsigned short*)(ws + CTX);
  unsigned short* mqk  = (unsigned short*)(ws + MQK);
  unsigned short* mvp  = (unsigned short*)(ws + MVP);
  float* bqk = (float*)(ws + BQK);
  float* bvp = (float*)(ws + BVP);
  unsigned short* wqkvs = (unsigned short*)(ws + WQKVS);
  float* bqkvs = (float*)(ws + BQKVS);
  unsigned short* wps = (unsigned short*)(ws + WPS);
  unsigned short* w1t = (unsigned short*)(ws + W1T), *w2t = (unsigned short*)(ws + W2T);
  unsigned short* qn_c = (unsigned short*)(ws + QN_C);
  float* pes = (float*)(ws + PES);
  float*          x1   = (float*)(ws + X1);
  unsigned short* qn_s = (unsigned short*)(ws + QN_S);
  unsigned short* vn_s = (unsigned short*)(ws + VN_S);
  float* qkv_s = (float*)(ws + QKV_S);
  unsigned short* s_o  = (unsigned short*)(ws + S_O);
  float*          x2   = (float*)(ws + X2);
  unsigned short* ffn_n = (unsigned short*)(ws + FFN);
  unsigned short* h1    = (unsigned short*)(ws + H1);

  // 1. all prep (weights, folded matrices, LN(pooled), pe sums) in one launch
  prep_all<<<6018, 256, 0, stream>>>(
      Wq_s, Wk_s, Wv_s, Wp_s, W1, W2, Wq_c, Wk_c, Wv_c, Wp_c,
      bq_s, bv_s, bq_c, bv_c, bp_c, pooled, ln_qc_g, ln_qc_b, cross_pe,
      wqkvs, wps, w1t, w2t, mqk, mvp, bqk, bvp, bqkvs, qn_c, pes);

  // 2. q~ = qn_c @ Mqk^T + bqk
  gemm_bt<<<(BW_ / 64) * (2048 / 64), 256, 0, stream>>>(qn_c, mqk, BW_, 2048, 256,
      bqk, nullptr, nullptr, qt, 0);

  // 3. fused LN-transpose + cross attention (features -> ctx, no kn/vn)
  cross_fused<<<1056, 128, 0, stream>>>(features, cross_pe, qt,
      ln_kv_g, ln_kv_b, ln_vc_g, ln_vc_b, pes, ctx);

  // 4. x1 = ctx @ Mvp^T + bvp + pooled
  gemm_bt<<<(BW_ / 64) * (C_ / 64), 256, 0, stream>>>(ctx, mvp, BW_, C_, 2048,
      bvp, pooled, x1, nullptr, 0);

  // 5. qn_s = LN(x1+self_pe), vn_s = LN(x1)
  ln_dual<<<BW_, 256, 0, stream>>>(x1, self_pe, ln_qs_g, ln_qs_b,
                                   ln_vs_g, ln_vs_b, qn_s, vn_s);

  // 6. q|k from qn_s -> qkv_s cols [0,512); v from vn_s -> cols [512,768). ldc=768.
  gemm_bt_st<<<(BW_ / 64) * (512 / 64), 256, 0, stream>>>(qn_s, wqkvs, BW_, 512, 256,
      768, bqkvs, qkv_s);
  gemm_bt_st<<<(BW_ / 64) * (256 / 64), 256, 0, stream>>>(vn_s, wqkvs + 131072, BW_, 256, 256,
      768, bqkvs + 512, qkv_s + 512);

  // 7. self attention core
  self_attn3<<<B_ * 8, 192, 0, stream>>>(qkv_s, s_o);

  // 8. x2 = s_o @ Wp_s + bp_s + x1
  gemm_bt<<<(BW_ / 64) * (C_ / 64), 256, 0, stream>>>(s_o, wps, BW_, C_, C_,
      bp_s, x1, x2, nullptr, 0);

  // 9. FFN
  ln_rows<<<BW_, 256, 0, stream>>>(x2, ln_ffn_g, ln_ffn_b, ffn_n);
  gemm_bt<<<(BW_ / 64) * (F_ / 64), 256, 0, stream>>>(ffn_n, w1t, BW_, F_, C_,
      b1, nullptr, nullptr, h1, 1);
  gemm_bt<<<(BW_ / 64) * (C_ / 64), 256, 0, stream>>>(h1, w2t, BW_, C_, F_,
      b2, x2, outp, nullptr, 0);
}

// Round 10
// 487.920 us; speedup vs baseline: 1.1135x; 1.0034x over previous
//
#include <hip/hip_runtime.h>
#include <math.h>

// Problem dims
#define B_   48
#define W_   88
#define C_   256
#define H_   32
#define F_   1024
#define BW_  (B_ * W_)        // 4224
#define BWH_ (B_ * W_ * H_)   // 135168
#define HW_  (H_ * W_)        // 2816

typedef float  f32x4  __attribute__((ext_vector_type(4)));
typedef __bf16 bf16x8 __attribute__((ext_vector_type(8)));

__device__ __forceinline__ unsigned short f2bf(float f) {
  union { float f; unsigned int u; } v; v.f = f;
  unsigned int r = v.u + 0x7FFFu + ((v.u >> 16) & 1u);  // RNE
  return (unsigned short)(r >> 16);
}
__device__ __forceinline__ float bf2f(unsigned short h) {
  union { unsigned int u; float f; } v; v.u = ((unsigned int)h) << 16;
  return v.f;
}
__device__ __forceinline__ unsigned int pack2(float a, float b) {
  return (unsigned int)f2bf(a) | ((unsigned int)f2bf(b) << 16);
}

// DPP butterfly add (VALU pipe, no DS op). Butterfly over 32 lanes:
// L1 quad_perm xor1 (0xB1), L2 quad_perm xor2 (0x4E), L3 row_half_mirror
// (0x141), L4 row_mirror (0x140), L5 = xor16 shuffle.
template<int CTRL>
__device__ __forceinline__ float dppadd(float x) {
  union { float f; int i; } a, b;
  a.f = x;
  b.i = __builtin_amdgcn_update_dpp(0, a.i, CTRL, 0xF, 0xF, true);
  return x + b.f;
}

// ---------------------------------------------------------------------------
// prep_all: every weight-prep step in ONE launch.
//  blk [0,768)      : 32x32 LDS tile transposes f32[in,out] -> bf16[out,in]
//  blk [768,1280)   : Mqk build  (512 blocks: h x 64 c-chunks of 4)
//  blk [1280,1792)  : Mvp build  (512 blocks: h x 64 d-chunks of 4)
//  blk 1792         : bvp + bqkvs concat
//  blk [1793,6017)  : LN(pooled) -> qn_c bf16 (one row per block)
//  blk 6017         : cross_pe row sums (pes[2h]=sum, pes[2h+1]=sumsq)
// ---------------------------------------------------------------------------
__global__ __launch_bounds__(256) void prep_all(
    const float* __restrict__ Wq_s, const float* __restrict__ Wk_s,
    const float* __restrict__ Wv_s, const float* __restrict__ Wp_s,
    const float* __restrict__ W1, const float* __restrict__ W2,
    const float* __restrict__ Wq_c, const float* __restrict__ Wk_c,
    const float* __restrict__ Wv_c, const float* __restrict__ Wp_c,
    const float* __restrict__ bq_s, const float* __restrict__ bv_s,
    const float* __restrict__ bq_c, const float* __restrict__ bv_c,
    const float* __restrict__ bp_c,
    const float* __restrict__ pooled,
    const float* __restrict__ ln_qc_g, const float* __restrict__ ln_qc_b,
    const float* __restrict__ cross_pe,
    unsigned short* __restrict__ wqkvs, unsigned short* __restrict__ wps,
    unsigned short* __restrict__ w1t, unsigned short* __restrict__ w2t,
    unsigned short* __restrict__ mqk, unsigned short* __restrict__ mvp,
    float* __restrict__ bqk, float* __restrict__ bvp,
    float* __restrict__ bqkvs, unsigned short* __restrict__ qn_c,
    float* __restrict__ pes) {
  __shared__ float smem[256 * 33 + 4 * 33];
  int blk = blockIdx.x, t = threadIdx.x;

  if (blk < 768) {
    // ---- weight tile transpose ----
    const float* src; unsigned short* dst; int Cc, R, tile;
    if (blk < 64)       { src = Wq_s; dst = wqkvs;          Cc = 256;  R = 256;  tile = blk; }
    else if (blk < 128) { src = Wk_s; dst = wqkvs + 65536;  Cc = 256;  R = 256;  tile = blk - 64; }
    else if (blk < 192) { src = Wv_s; dst = wqkvs + 131072; Cc = 256;  R = 256;  tile = blk - 128; }
    else if (blk < 256) { src = Wp_s; dst = wps;            Cc = 256;  R = 256;  tile = blk - 192; }
    else if (blk < 512) { src = W1;   dst = w1t;            Cc = 1024; R = 256;  tile = blk - 256; }
    else                { src = W2;   dst = w2t;            Cc = 256;  R = 1024; tile = blk - 512; }
    int tcn = Cc >> 5;
    int tr = tile / tcn, tc = tile % tcn;
    float (*lds)[33] = (float(*)[33])smem;
    int r = t >> 3, c4 = (t & 7) * 4;
    float4 v = *(const float4*)(src + (size_t)(tr * 32 + r) * Cc + tc * 32 + c4);
    lds[r][c4 + 0] = v.x; lds[r][c4 + 1] = v.y; lds[r][c4 + 2] = v.z; lds[r][c4 + 3] = v.w;
    __syncthreads();
    // dst[(tc*32+rd)][tr*32 + cd] = src[tr*32+cd][tc*32+rd]
    int rd = t >> 3, cd4 = (t & 7) * 4;
    unsigned int u0 = pack2(lds[cd4 + 0][rd], lds[cd4 + 1][rd]);
    unsigned int u1 = pack2(lds[cd4 + 2][rd], lds[cd4 + 3][rd]);
    uint2 u; u.x = u0; u.y = u1;
    *(uint2*)(dst + (size_t)(tc * 32 + rd) * R + tr * 32 + cd4) = u;
  } else if (blk < 1280) {
    // ---- Mqk[n=256h+c][dp] = scale * sum_dd Wq_c[dp,32h+dd]*Wk_c[c,32h+dd]
    int lb = blk - 768;
    int h = lb >> 6, cb = lb & 63;
    float (*wq)[33] = (float(*)[33])smem;               // [256 dp][32 dd]
    float (*wk)[33] = (float(*)[33])(smem + 256 * 33);  // [4 c][32 dd]
#pragma unroll
    for (int p = 0; p < 8; p++) {
      int dp = (t >> 3) + 32 * p, d4 = (t & 7) * 4;
      float4 v = *(const float4*)(Wq_c + (size_t)dp * 256 + 32 * h + d4);
      wq[dp][d4 + 0] = v.x; wq[dp][d4 + 1] = v.y; wq[dp][d4 + 2] = v.z; wq[dp][d4 + 3] = v.w;
    }
    if (t < 128) {
      int c_l = t >> 5, dd = t & 31;
      wk[c_l][dd] = Wk_c[(size_t)(cb * 4 + c_l) * 256 + 32 * h + dd];
    }
    __syncthreads();
    const float scale = 0.17677669529663689f;
    int c_l = t >> 6, ln = t & 63;
    int n = 256 * h + cb * 4 + c_l;
#pragma unroll
    for (int j = 0; j < 4; j++) {
      int dp = ln + 64 * j;
      float acc = 0.f;
#pragma unroll
      for (int dd = 0; dd < 32; dd++) acc += wq[dp][dd] * wk[c_l][dd];
      mqk[(size_t)n * 256 + dp] = f2bf(acc * scale);
    }
    if (ln == 0) {
      float bb = 0.f;
#pragma unroll
      for (int dd = 0; dd < 32; dd++) bb += bq_c[32 * h + dd] * wk[c_l][dd];
      bqk[n] = bb * scale;
    }
  } else if (blk < 1792) {
    // ---- Mvp[d][256h+c] = sum_dd Wv_c[c,32h+dd]*Wp_c[32h+dd,d]
    int lb = blk - 1280;
    int h = lb >> 6, db = lb & 63;
    float (*wv)[33] = (float(*)[33])smem;
    float (*wp)[33] = (float(*)[33])(smem + 256 * 33);
#pragma unroll
    for (int p = 0; p < 8; p++) {
      int c = (t >> 3) + 32 * p, d4 = (t & 7) * 4;
      float4 v = *(const float4*)(Wv_c + (size_t)c * 256 + 32 * h + d4);
      wv[c][d4 + 0] = v.x; wv[c][d4 + 1] = v.y; wv[c][d4 + 2] = v.z; wv[c][d4 + 3] = v.w;
    }
    if (t < 128) {
      int d_l = t >> 5, dd = t & 31;
      wp[d_l][dd] = Wp_c[(size_t)(32 * h + dd) * 256 + db * 4 + d_l];
    }
    __syncthreads();
    int d_l = t >> 6, ln = t & 63;
    int d = db * 4 + d_l;
#pragma unroll
    for (int j = 0; j < 4; j++) {
      int c = ln + 64 * j;
      float acc = 0.f;
#pragma unroll
      for (int dd = 0; dd < 32; dd++) acc += wv[c][dd] * wp[d_l][dd];
      mvp[(size_t)d * 2048 + 256 * h + c] = f2bf(acc);
    }
  } else if (blk == 1792) {
    // ---- bvp + bqkvs ----
    float acc = bp_c[t];
    for (int dp = 0; dp < 256; dp++) acc += bv_c[dp] * Wp_c[(size_t)dp * 256 + t];
    bvp[t] = acc;
    bqkvs[t] = bq_s[t]; bqkvs[256 + t] = 0.f; bqkvs[512 + t] = bv_s[t];
  } else if (blk < 6017) {
    // ---- LN(pooled) row -> qn_c ----
    int row = blk - 1793, c = t;
    float v = pooled[(size_t)row * C_ + c];
    float s1 = v, s2 = v * v;
#pragma unroll
    for (int m = 32; m > 0; m >>= 1) {
      s1 += __shfl_xor(s1, m, 64); s2 += __shfl_xor(s2, m, 64);
    }
    float* red = smem;
    int wave = c >> 6;
    if ((c & 63) == 0) { red[wave] = s1; red[4 + wave] = s2; }
    __syncthreads();
    s1 = red[0] + red[1] + red[2] + red[3];
    s2 = red[4] + red[5] + red[6] + red[7];
    float mu = s1 * (1.f / C_);
    float rs = rsqrtf(s2 * (1.f / C_) - mu * mu + 1e-5f);
    qn_c[(size_t)row * C_ + c] = f2bf((v - mu) * rs * ln_qc_g[c] + ln_qc_b[c]);
  } else {
    // ---- cross_pe per-row sums: pes[2h]=sum_c pe, pes[2h+1]=sum_c pe^2 ----
    int h = t >> 3, seg = t & 7;
    const float* pr = cross_pe + (size_t)h * 256 + seg * 32;
    float s1 = 0.f, s2 = 0.f;
#pragma unroll
    for (int i = 0; i < 32; i++) { float v = pr[i]; s1 += v; s2 += v * v; }
    s1 += __shfl_xor(s1, 1, 8); s2 += __shfl_xor(s2, 1, 8);
    s1 += __shfl_xor(s1, 2, 8); s2 += __shfl_xor(s2, 2, 8);
    s1 += __shfl_xor(s1, 4, 8); s2 += __shfl_xor(s2, 4, 8);
    if (seg == 0) { pes[2 * h] = s1; pes[2 * h + 1] = s2; }
  }
}

// ---------------------------------------------------------------------------
// cross_fused v7 = v6 (DPP tree, verified R9: 117us) widened to 8-w chunks,
// 256 threads, 528 blocks. R9 analysis: kernel runs at the effective
// delivery rate of the scattered feature read (~1.2 TB/s); loads were 16B
// per 64B sector (25% utilization). v7 loads 32B contiguous per lane
// (lane = c row, 8 w's) -> 50% sector utilization. Reader/reduce/pipeline
// identical to v6 (w = t>>5 now 0..7). Math unchanged.
// ---------------------------------------------------------------------------
__global__ __launch_bounds__(256, 2) void cross_fused(
    const float* __restrict__ features, const float* __restrict__ cross_pe,
    const unsigned short* __restrict__ qt_g,
    const float* __restrict__ g_kv, const float* __restrict__ b_kv,
    const float* __restrict__ g_vc, const float* __restrict__ b_vc,
    const float* __restrict__ pes,
    unsigned short* __restrict__ ctx_g) {
  __shared__ __attribute__((aligned(16))) float stage[2 * 8 * 268];
  const int p = blockIdx.x;
  const int xcd = p & 7, slot = p >> 3;       // slot 0..65
  const int b = xcd + 8 * (slot / 11);        // all 11 w-chunks of b on one XCD
  const int w0 = (slot % 11) * 8;
  const int t = threadIdx.x;                  // 0..255
  const int bw0 = b * 88 + w0;
  const int w = t >> 5, c8 = t & 31, cbase = c8 << 3;

  // ---- one-time: qg = q*gk in registers; Qg = sum q*gk; Qb = sum q*bk ----
  float qg[8][8], Qg[8], Qb[8];
  {
    float gk8[8], bk8[8];
    float4 u0 = *(const float4*)(g_kv + cbase), u1 = *(const float4*)(g_kv + cbase + 4);
    gk8[0]=u0.x; gk8[1]=u0.y; gk8[2]=u0.z; gk8[3]=u0.w;
    gk8[4]=u1.x; gk8[5]=u1.y; gk8[6]=u1.z; gk8[7]=u1.w;
    u0 = *(const float4*)(b_kv + cbase); u1 = *(const float4*)(b_kv + cbase + 4);
    bk8[0]=u0.x; bk8[1]=u0.y; bk8[2]=u0.z; bk8[3]=u0.w;
    bk8[4]=u1.x; bk8[5]=u1.y; bk8[6]=u1.z; bk8[7]=u1.w;
    const unsigned short* qrow = qt_g + (size_t)(bw0 + w) * 2048 + cbase;
#pragma unroll
    for (int hd = 0; hd < 8; hd++) {
      bf16x8 qv = *(const bf16x8*)(qrow + hd * 256);
      float sg = 0.f, sb = 0.f;
#pragma unroll
      for (int i = 0; i < 8; i++) {
        float qf = (float)qv[i];
        qg[hd][i] = qf * gk8[i];
        sg += qg[hd][i];
        sb += qf * bk8[i];
      }
      Qg[hd] = sg; Qb[hd] = sb;
    }
#pragma unroll
    for (int m = 1; m < 32; m <<= 1) {
#pragma unroll
      for (int hd = 0; hd < 8; hd++) {
        Qg[hd] += __shfl_xor(Qg[hd], m, 32);
        Qb[hd] += __shfl_xor(Qb[hd], m, 32);
      }
    }
  }

  float accA[8][8];
  float accB[8], l[8];
#pragma unroll
  for (int hd = 0; hd < 8; hd++) {
    accB[hd] = 0.f; l[hd] = 0.f;
#pragma unroll
    for (int i = 0; i < 8; i++) accA[hd][i] = 0.f;
  }

  const float* fbase = features + (size_t)b * (C_ * HW_) + w0;  // + c*2816 + h*88
  // loader role: thread t owns row c = t; 32B contiguous = the 8 w's.
  // 2-deep prologue: X = h0, Y = h1.
  float4 x0 = *(const float4*)(fbase + (size_t)t * HW_);
  float4 x1 = *(const float4*)(fbase + (size_t)t * HW_ + 4);
  float4 y0 = *(const float4*)(fbase + (size_t)t * HW_ + 88);
  float4 y1 = *(const float4*)(fbase + (size_t)t * HW_ + 92);

  // pe row for current step (h=0); pes pair for step 0
  float peC[8];
  {
    float4 q0 = *(const float4*)(cross_pe + cbase);
    float4 q1 = *(const float4*)(cross_pe + cbase + 4);
    peC[0]=q0.x; peC[1]=q0.y; peC[2]=q0.z; peC[3]=q0.w;
    peC[4]=q1.x; peC[5]=q1.y; peC[6]=q1.z; peC[7]=q1.w;
  }
  float pesC1 = pes[0], pesC2 = pes[1];

  // pipeline state: lane-partials + vls of the PREVIOUS h
  float ps1, ps2, pu, pS[8], vprev[8];

  // ---- phase 0 (peeled: dots only, no tree/accumulate yet) ----
  {
    float* st = stage;
    st[0 * 268 + t] = x0.x; st[1 * 268 + t] = x0.y;
    st[2 * 268 + t] = x0.z; st[3 * 268 + t] = x0.w;
    st[4 * 268 + t] = x1.x; st[5 * 268 + t] = x1.y;
    st[6 * 268 + t] = x1.z; st[7 * 268 + t] = x1.w;
    asm volatile("s_waitcnt lgkmcnt(0)" ::: "memory");
    __builtin_amdgcn_s_barrier();
    asm volatile("" ::: "memory");
    // prefetch h=2 into X
    x0 = *(const float4*)(fbase + (size_t)t * HW_ + 2 * 88);
    x1 = *(const float4*)(fbase + (size_t)t * HW_ + 2 * 88 + 4);
    const float* sr = st + w * 268 + cbase;
    float4 v0 = *(const float4*)(sr);
    float4 v1 = *(const float4*)(sr + 4);
    float vls[8] = {v0.x, v0.y, v0.z, v0.w, v1.x, v1.y, v1.z, v1.w};
    // prefetch pe for h=1
    float peN[8];
    {
      float4 q0 = *(const float4*)(cross_pe + 256 + cbase);
      float4 q1 = *(const float4*)(cross_pe + 256 + cbase + 4);
      peN[0]=q0.x; peN[1]=q0.y; peN[2]=q0.z; peN[3]=q0.w;
      peN[4]=q1.x; peN[5]=q1.y; peN[6]=q1.z; peN[7]=q1.w;
    }
    // dots for h=0
    float s1 = 0.f, s2 = 0.f, sp = 0.f, vp[8];
#pragma unroll
    for (int i = 0; i < 8; i++) {
      float v = vls[i];
      vp[i] = v + peC[i];
      s1 += v; s2 += v * v; sp += v * peC[i];
    }
#pragma unroll
    for (int hd = 0; hd < 8; hd++) {
      float a = 0.f;
#pragma unroll
      for (int i = 0; i < 8; i++) a += qg[hd][i] * vp[i];
      pS[hd] = a;
    }
    ps1 = s1; ps2 = s2; pu = s2 + 2.f * sp;
#pragma unroll
    for (int i = 0; i < 8; i++) vprev[i] = vls[i];
    // rotate X<->Y, pe  (pesC stays = pes of step 0, consumed in phase 1)
    float4 t0 = x0, t1 = x1;
    x0 = y0; x1 = y1; y0 = t0; y1 = t1;
#pragma unroll
    for (int i = 0; i < 8; i++) peC[i] = peN[i];
  }

  // ---- phases h = 1..31: stage/read/dot(h) overlapped with tree/acc(h-1) ----
  for (int h = 1; h < 32; ++h) {
    float* st = stage + (h & 1) * (8 * 268);
    st[0 * 268 + t] = x0.x; st[1 * 268 + t] = x0.y;
    st[2 * 268 + t] = x0.z; st[3 * 268 + t] = x0.w;
    st[4 * 268 + t] = x1.x; st[5 * 268 + t] = x1.y;
    st[6 * 268 + t] = x1.z; st[7 * 268 + t] = x1.w;
    asm volatile("s_waitcnt lgkmcnt(0)" ::: "memory");
    __builtin_amdgcn_s_barrier();
    asm volatile("" ::: "memory");
    if (h < 30) {
      x0 = *(const float4*)(fbase + (size_t)t * HW_ + (h + 2) * 88);
      x1 = *(const float4*)(fbase + (size_t)t * HW_ + (h + 2) * 88 + 4);
    }
    // issue LDS read for step h early
    const float* sr = st + w * 268 + cbase;
    float4 v0 = *(const float4*)(sr);
    float4 v1 = *(const float4*)(sr + 4);
    // ---- TREE for step h-1: levels 1-4 on DPP (VALU), level 16 via shuffle
    ps1 = dppadd<0xB1>(ps1); ps2 = dppadd<0xB1>(ps2); pu = dppadd<0xB1>(pu);
#pragma unroll
    for (int hd = 0; hd < 8; hd++) pS[hd] = dppadd<0xB1>(pS[hd]);
    ps1 = dppadd<0x4E>(ps1); ps2 = dppadd<0x4E>(ps2); pu = dppadd<0x4E>(pu);
#pragma unroll
    for (int hd = 0; hd < 8; hd++) pS[hd] = dppadd<0x4E>(pS[hd]);
    ps1 = dppadd<0x141>(ps1); ps2 = dppadd<0x141>(ps2); pu = dppadd<0x141>(pu);
#pragma unroll
    for (int hd = 0; hd < 8; hd++) pS[hd] = dppadd<0x141>(pS[hd]);
    ps1 = dppadd<0x140>(ps1); ps2 = dppadd<0x140>(ps2); pu = dppadd<0x140>(pu);
#pragma unroll
    for (int hd = 0; hd < 8; hd++) pS[hd] = dppadd<0x140>(pS[hd]);
    ps1 += __shfl_xor(ps1, 16, 32);
    ps2 += __shfl_xor(ps2, 16, 32);
    pu  += __shfl_xor(pu, 16, 32);
#pragma unroll
    for (int hd = 0; hd < 8; hd++) pS[hd] += __shfl_xor(pS[hd], 16, 32);
    // prefetch pe for h+1
    float peN[8];
    if (h < 31) {
      float4 q0 = *(const float4*)(cross_pe + (h + 1) * 256 + cbase);
      float4 q1 = *(const float4*)(cross_pe + (h + 1) * 256 + cbase + 4);
      peN[0]=q0.x; peN[1]=q0.y; peN[2]=q0.z; peN[3]=q0.w;
      peN[4]=q1.x; peN[5]=q1.y; peN[6]=q1.z; peN[7]=q1.w;
    } else {
#pragma unroll
      for (int i = 0; i < 8; i++) peN[i] = 0.f;
    }
    // ---- dots for step h (vls ready by now)
    float vls[8] = {v0.x, v0.y, v0.z, v0.w, v1.x, v1.y, v1.z, v1.w};
    float s1 = 0.f, s2 = 0.f, sp = 0.f, vp[8];
#pragma unroll
    for (int i = 0; i < 8; i++) {
      float v = vls[i];
      vp[i] = v + peC[i];
      s1 += v; s2 += v * v; sp += v * peC[i];
    }
    float nS[8];
#pragma unroll
    for (int hd = 0; hd < 8; hd++) {
      float a = 0.f;
#pragma unroll
      for (int i = 0; i < 8; i++) a += qg[hd][i] * vp[i];
      nS[hd] = a;
    }
    // ---- scalars + softmax accumulate for step h-1 (tree results ready)
    {
      float mu_v = ps1 * (1.f / 256.f);
      float rs_v = rsqrtf(ps2 * (1.f / 256.f) - mu_v * mu_v + 1e-5f);
      float mu_k = (ps1 + pesC1) * (1.f / 256.f);
      float rs_k = rsqrtf((pu + pesC2) * (1.f / 256.f) - mu_k * mu_k + 1e-5f);
#pragma unroll
      for (int hd = 0; hd < 8; hd++) {
        float sc = rs_k * (pS[hd] - mu_k * Qg[hd]) + Qb[hd];
        float e = __expf(sc);
        float er = e * rs_v;
        l[hd] += e;
        accB[hd] += er * mu_v;
#pragma unroll
        for (int i = 0; i < 8; i++) accA[hd][i] += er * vprev[i];
      }
    }
    // ---- rotate pipeline state
    ps1 = s1; ps2 = s2; pu = s2 + 2.f * sp;
#pragma unroll
    for (int hd = 0; hd < 8; hd++) pS[hd] = nS[hd];
#pragma unroll
    for (int i = 0; i < 8; i++) { vprev[i] = vls[i]; peC[i] = peN[i]; }
    pesC1 = pes[2 * h]; pesC2 = pes[2 * h + 1];
    float4 t0 = x0, t1 = x1;
    x0 = y0; x1 = y1; y0 = t0; y1 = t1;
  }

  // ---- epilogue: tree + scalars + accumulate for h=31 ----
  {
    ps1 = dppadd<0xB1>(ps1); ps2 = dppadd<0xB1>(ps2); pu = dppadd<0xB1>(pu);
#pragma unroll
    for (int hd = 0; hd < 8; hd++) pS[hd] = dppadd<0xB1>(pS[hd]);
    ps1 = dppadd<0x4E>(ps1); ps2 = dppadd<0x4E>(ps2); pu = dppadd<0x4E>(pu);
#pragma unroll
    for (int hd = 0; hd < 8; hd++) pS[hd] = dppadd<0x4E>(pS[hd]);
    ps1 = dppadd<0x141>(ps1); ps2 = dppadd<0x141>(ps2); pu = dppadd<0x141>(pu);
#pragma unroll
    for (int hd = 0; hd < 8; hd++) pS[hd] = dppadd<0x141>(pS[hd]);
    ps1 = dppadd<0x140>(ps1); ps2 = dppadd<0x140>(ps2); pu = dppadd<0x140>(pu);
#pragma unroll
    for (int hd = 0; hd < 8; hd++) pS[hd] = dppadd<0x140>(pS[hd]);
    ps1 += __shfl_xor(ps1, 16, 32);
    ps2 += __shfl_xor(ps2, 16, 32);
    pu  += __shfl_xor(pu, 16, 32);
#pragma unroll
    for (int hd = 0; hd < 8; hd++) pS[hd] += __shfl_xor(pS[hd], 16, 32);
    float mu_v = ps1 * (1.f / 256.f);
    float rs_v = rsqrtf(ps2 * (1.f / 256.f) - mu_v * mu_v + 1e-5f);
    float mu_k = (ps1 + pesC1) * (1.f / 256.f);
    float rs_k = rsqrtf((pu + pesC2) * (1.f / 256.f) - mu_k * mu_k + 1e-5f);
#pragma unroll
    for (int hd = 0; hd < 8; hd++) {
      float sc = rs_k * (pS[hd] - mu_k * Qg[hd]) + Qb[hd];
      float e = __expf(sc);
      float er = e * rs_v;
      l[hd] += e;
      accB[hd] += er * mu_v;
#pragma unroll
      for (int i = 0; i < 8; i++) accA[hd][i] += er * vprev[i];
    }
  }

  // epilogue: ctx = gv*(accA-accB)/l + bv -> bf16
  float gv8[8], bv8[8];
  {
    float4 u0 = *(const float4*)(g_vc + cbase), u1 = *(const float4*)(g_vc + cbase + 4);
    gv8[0]=u0.x; gv8[1]=u0.y; gv8[2]=u0.z; gv8[3]=u0.w;
    gv8[4]=u1.x; gv8[5]=u1.y; gv8[6]=u1.z; gv8[7]=u1.w;
    u0 = *(const float4*)(b_vc + cbase); u1 = *(const float4*)(b_vc + cbase + 4);
    bv8[0]=u0.x; bv8[1]=u0.y; bv8[2]=u0.z; bv8[3]=u0.w;
    bv8[4]=u1.x; bv8[5]=u1.y; bv8[6]=u1.z; bv8[7]=u1.w;
  }
  unsigned short* orow = ctx_g + (size_t)(bw0 + w) * 2048 + cbase;
#pragma unroll
  for (int hd = 0; hd < 8; hd++) {
    float inv = 1.f / l[hd];
    unsigned short pk[8];
#pragma unroll
    for (int i = 0; i < 8; i++)
      pk[i] = f2bf(gv8[i] * (accA[hd][i] - accB[hd]) * inv + bv8[i]);
    *(uint4*)(orow + hd * 256) = *(uint4*)pk;
  }
}

// ---------------------------------------------------------------------------
// Row LayerNorm: x f32 [rows, C_] -> bf16 out
// ---------------------------------------------------------------------------
__global__ __launch_bounds__(256) void ln_rows(
    const float* __restrict__ x,
    const float* __restrict__ g, const float* __restrict__ bta,
    unsigned short* __restrict__ out) {
  int row = blockIdx.x, c = threadIdx.x;
  float v = x[(size_t)row * C_ + c];
  float s1 = v, s2 = v * v;
#pragma unroll
  for (int m = 32; m > 0; m >>= 1) {
    s1 += __shfl_xor(s1, m, 64);
    s2 += __shfl_xor(s2, m, 64);
  }
  __shared__ float red[8];
  int wave = c >> 6;
  if ((c & 63) == 0) { red[wave] = s1; red[4 + wave] = s2; }
  __syncthreads();
  s1 = red[0] + red[1] + red[2] + red[3];
  s2 = red[4] + red[5] + red[6] + red[7];
  float mu = s1 * (1.f / C_);
  float rs = rsqrtf(s2 * (1.f / C_) - mu * mu + 1e-5f);
  out[(size_t)row * C_ + c] = f2bf((v - mu) * rs * g[c] + bta[c]);
}

// ---------------------------------------------------------------------------
// ln_dual: out1 = LN(x+pe)*g1+b1, out2 = LN(x)*g2+b2. One read of x.
// ---------------------------------------------------------------------------
__global__ __launch_bounds__(256) void ln_dual(
    const float* __restrict__ x, const float* __restrict__ pe,
    const float* __restrict__ g1, const float* __restrict__ b1a,
    const float* __restrict__ g2, const float* __restrict__ b2a,
    unsigned short* __restrict__ out1, unsigned short* __restrict__ out2) {
  int row = blockIdx.x, c = threadIdx.x;
  float v = x[(size_t)row * C_ + c];
  float vp = v + pe[(size_t)(row % 88) * C_ + c];
  float s1 = v, s2 = v * v, t1 = vp, t2 = vp * vp;
#pragma unroll
  for (int m = 32; m > 0; m >>= 1) {
    s1 += __shfl_xor(s1, m, 64); s2 += __shfl_xor(s2, m, 64);
    t1 += __shfl_xor(t1, m, 64); t2 += __shfl_xor(t2, m, 64);
  }
  __shared__ float red[16];
  int wave = c >> 6;
  if ((c & 63) == 0) {
    red[wave] = s1; red[4 + wave] = s2; red[8 + wave] = t1; red[12 + wave] = t2;
  }
  __syncthreads();
  s1 = red[0] + red[1] + red[2] + red[3];
  s2 = red[4] + red[5] + red[6] + red[7];
  t1 = red[8] + red[9] + red[10] + red[11];
  t2 = red[12] + red[13] + red[14] + red[15];
  float mu = s1 * (1.f / C_), rs = rsqrtf(s2 * (1.f / C_) - mu * mu + 1e-5f);
  float mup = t1 * (1.f / C_), rsp = rsqrtf(t2 * (1.f / C_) - mup * mup + 1e-5f);
  out1[(size_t)row * C_ + c] = f2bf((vp - mup) * rsp * g1[c] + b1a[c]);
  out2[(size_t)row * C_ + c] = f2bf((v - mu) * rs * g2[c] + b2a[c]);
}

// ---------------------------------------------------------------------------
// GEMM: out[M,N] = A[M,K](bf16) @ Bt[N,K](bf16)^T, fp32 acc.
// Register double-buffer: next K-tile loads overlap current MFMA phase.
// ---------------------------------------------------------------------------
__global__ __launch_bounds__(256) void gemm_bt(
    const unsigned short* __restrict__ A, const unsigned short* __restrict__ Bt,
    int M, int N, int K,
    const float* __restrict__ bias, const float* __restrict__ resid,
    float* __restrict__ outF, unsigned short* __restrict__ outB, int act_gelu) {
  __shared__ __attribute__((aligned(16))) unsigned short As[64][32];
  __shared__ __attribute__((aligned(16))) unsigned short Bs[64][32];
  const int tiles_n = N >> 6;
  const int bm = blockIdx.x / tiles_n;
  const int bn = blockIdx.x % tiles_n;
  const int tid = threadIdx.x;
  const int wave = tid >> 6, lane = tid & 63;
  const int quad = lane >> 4, lr = lane & 15;
  const int wm = (wave >> 1) << 5, wn = (wave & 1) << 5;
  const int lrow = tid >> 2;
  const int lcol = (tid & 3) << 3;
  const size_t a_base = (size_t)(bm * 64 + lrow) * K + lcol;
  const size_t b_base = (size_t)(bn * 64 + lrow) * K + lcol;
  f32x4 acc[2][2] = {};
  uint4 areg = *(const uint4*)(A + a_base);
  uint4 breg = *(const uint4*)(Bt + b_base);
  for (int k0 = 0; k0 < K; k0 += 32) {
    *(uint4*)&As[lrow][lcol] = areg;
    *(uint4*)&Bs[lrow][lcol] = breg;
    __syncthreads();
    if (k0 + 32 < K) {
      areg = *(const uint4*)(A + a_base + k0 + 32);
      breg = *(const uint4*)(Bt + b_base + k0 + 32);
    }
    bf16x8 af0 = *(const bf16x8*)&As[wm + lr][quad << 3];
    bf16x8 af1 = *(const bf16x8*)&As[wm + 16 + lr][quad << 3];
    bf16x8 bf0 = *(const bf16x8*)&Bs[wn + lr][quad << 3];
    bf16x8 bf1 = *(const bf16x8*)&Bs[wn + 16 + lr][quad << 3];
    acc[0][0] = __builtin_amdgcn_mfma_f32_16x16x32_bf16(af0, bf0, acc[0][0], 0, 0, 0);
    acc[0][1] = __builtin_amdgcn_mfma_f32_16x16x32_bf16(af0, bf1, acc[0][1], 0, 0, 0);
    acc[1][0] = __builtin_amdgcn_mfma_f32_16x16x32_bf16(af1, bf0, acc[1][0], 0, 0, 0);
    acc[1][1] = __builtin_amdgcn_mfma_f32_16x16x32_bf16(af1, bf1, acc[1][1], 0, 0, 0);
    __syncthreads();
  }
#pragma unroll
  for (int i = 0; i < 2; i++)
#pragma unroll
    for (int j = 0; j < 2; j++)
#pragma unroll
      for (int rr = 0; rr < 4; rr++) {
        int row = bm * 64 + wm + i * 16 + quad * 4 + rr;
        int col = bn * 64 + wn + j * 16 + lr;
        float val = acc[i][j][rr];
        if (bias) val += bias[col];
        if (act_gelu) val = 0.5f * val * (1.f + erff(val * 0.70710678118654752f));
        if (resid) val += resid[(size_t)row * N + col];
        if (outF) outF[(size_t)row * N + col] = val;
        else outB[(size_t)row * N + col] = f2bf(val);
      }
}

// ---------------------------------------------------------------------------
// gemm_bt_st: like gemm_bt but writes f32 with row stride ldc (+bias).
// ---------------------------------------------------------------------------
__global__ __launch_bounds__(256) void gemm_bt_st(
    const unsigned short* __restrict__ A, const unsigned short* __restrict__ Bt,
    int M, int N, int K, int ldc,
    const float* __restrict__ bias, float* __restrict__ outF) {
  __shared__ __attribute__((aligned(16))) unsigned short As[64][32];
  __shared__ __attribute__((aligned(16))) unsigned short Bs[64][32];
  const int tiles_n = N >> 6;
  const int bm = blockIdx.x / tiles_n;
  const int bn = blockIdx.x % tiles_n;
  const int tid = threadIdx.x;
  const int wave = tid >> 6, lane = tid & 63;
  const int quad = lane >> 4, lr = lane & 15;
  const int wm = (wave >> 1) << 5, wn = (wave & 1) << 5;
  const int lrow = tid >> 2;
  const int lcol = (tid & 3) << 3;
  const size_t a_base = (size_t)(bm * 64 + lrow) * K + lcol;
  const size_t b_base = (size_t)(bn * 64 + lrow) * K + lcol;
  f32x4 acc[2][2] = {};
  uint4 areg = *(const uint4*)(A + a_base);
  uint4 breg = *(const uint4*)(Bt + b_base);
  for (int k0 = 0; k0 < K; k0 += 32) {
    *(uint4*)&As[lrow][lcol] = areg;
    *(uint4*)&Bs[lrow][lcol] = breg;
    __syncthreads();
    if (k0 + 32 < K) {
      areg = *(const uint4*)(A + a_base + k0 + 32);
      breg = *(const uint4*)(Bt + b_base + k0 + 32);
    }
    bf16x8 af0 = *(const bf16x8*)&As[wm + lr][quad << 3];
    bf16x8 af1 = *(const bf16x8*)&As[wm + 16 + lr][quad << 3];
    bf16x8 bf0 = *(const bf16x8*)&Bs[wn + lr][quad << 3];
    bf16x8 bf1 = *(const bf16x8*)&Bs[wn + 16 + lr][quad << 3];
    acc[0][0] = __builtin_amdgcn_mfma_f32_16x16x32_bf16(af0, bf0, acc[0][0], 0, 0, 0);
    acc[0][1] = __builtin_amdgcn_mfma_f32_16x16x32_bf16(af0, bf1, acc[0][1], 0, 0, 0);
    acc[1][0] = __builtin_amdgcn_mfma_f32_16x16x32_bf16(af1, bf0, acc[1][0], 0, 0, 0);
    acc[1][1] = __builtin_amdgcn_mfma_f32_16x16x32_bf16(af1, bf1, acc[1][1], 0, 0, 0);
    __syncthreads();
  }
#pragma unroll
  for (int i = 0; i < 2; i++)
#pragma unroll
    for (int j = 0; j < 2; j++)
#pragma unroll
      for (int rr = 0; rr < 4; rr++) {
        int row = bm * 64 + wm + i * 16 + quad * 4 + rr;
        int col = bn * 64 + wn + j * 16 + lr;
        outF[(size_t)row * ldc + col] = acc[i][j][rr] + bias[col];
      }
}

// ---------------------------------------------------------------------------
// self_attn3: block=(b,h), 192 threads: pair (r=t>>1, dh=t&1) per query row.
// qkv f32 [BW_,768] (q+0,k+256,v+512). Scores in registers (44/lane).
// ---------------------------------------------------------------------------
__global__ __launch_bounds__(192) void self_attn3(
    const float* __restrict__ qkv, unsigned short* __restrict__ out) {
  int b = blockIdx.x >> 3;
  int h = blockIdx.x & 7;
  int t = threadIdx.x;
  __shared__ float kl[88][33];
  __shared__ float vl[88][33];
  for (int i = t; i < 704; i += 192) {
    int m = i >> 3, d4 = (i & 7) << 2;
    float4 kv4 = *(const float4*)(qkv + (size_t)(b * 88 + m) * 768 + 256 + h * 32 + d4);
    float4 vv4 = *(const float4*)(qkv + (size_t)(b * 88 + m) * 768 + 512 + h * 32 + d4);
    kl[m][d4 + 0] = kv4.x; kl[m][d4 + 1] = kv4.y; kl[m][d4 + 2] = kv4.z; kl[m][d4 + 3] = kv4.w;
    vl[m][d4 + 0] = vv4.x; vl[m][d4 + 1] = vv4.y; vl[m][d4 + 2] = vv4.z; vl[m][d4 + 3] = vv4.w;
  }
  __syncthreads();
  int r = t >> 1, dh = t & 1;
  if (r < 88) {
    const float* qrow = qkv + (size_t)(b * 88 + r) * 768 + h * 32;
    float qr[32];
#pragma unroll
    for (int g = 0; g < 8; g++) {
      float4 q4 = *(const float4*)(qrow + g * 4);
      qr[g * 4 + 0] = q4.x; qr[g * 4 + 1] = q4.y; qr[g * 4 + 2] = q4.z; qr[g * 4 + 3] = q4.w;
    }
    float sreg[44];
    float mx = -1e30f;
    int m0 = dh * 44;
    for (int mi = 0; mi < 44; mi++) {
      const float* krow = kl[m0 + mi];
      float s = 0.f;
#pragma unroll
      for (int d = 0; d < 32; d++) s += qr[d] * krow[d];
      s *= 0.17677669529663689f;
      sreg[mi] = s;
      mx = fmaxf(mx, s);
    }
    mx = fmaxf(mx, __shfl_xor(mx, 1, 64));
    float sum = 0.f;
    for (int mi = 0; mi < 44; mi++) { float e = __expf(sreg[mi] - mx); sreg[mi] = e; sum += e; }
    sum += __shfl_xor(sum, 1, 64);
    float inv = 1.f / sum;
    float o[32];
#pragma unroll
    for (int d = 0; d < 32; d++) o[d] = 0.f;
    for (int mi = 0; mi < 44; mi++) {
      float p = sreg[mi] * inv;
      const float* vrow = vl[m0 + mi];
#pragma unroll
      for (int d = 0; d < 32; d++) o[d] += p * vrow[d];
    }
#pragma unroll
    for (int d = 0; d < 32; d++) o[d] += __shfl_xor(o[d], 1, 64);
    unsigned short* orow = out + (size_t)(b * 88 + r) * 256 + h * 32 + dh * 16;
    uint4 u0, u1;
    int d0 = dh * 16;
    u0.x = pack2(o[d0 + 0], o[d0 + 1]);  u0.y = pack2(o[d0 + 2], o[d0 + 3]);
    u0.z = pack2(o[d0 + 4], o[d0 + 5]);  u0.w = pack2(o[d0 + 6], o[d0 + 7]);
    u1.x = pack2(o[d0 + 8], o[d0 + 9]);  u1.y = pack2(o[d0 + 10], o[d0 + 11]);
    u1.z = pack2(o[d0 + 12], o[d0 + 13]); u1.w = pack2(o[d0 + 14], o[d0 + 15]);
    *(uint4*)(orow) = u0;
    *(uint4*)(orow + 8) = u1;
  }
}

// ---------------------------------------------------------------------------
extern "C" void kernel_launch(void* const* d_in, const int* in_sizes, int n_in,
                              void* d_out, int out_size, void* d_ws, size_t ws_size,
                              hipStream_t stream) {
  (void)in_sizes; (void)n_in; (void)out_size; (void)ws_size;
  const float* pooled   = (const float*)d_in[0];
  const float* features = (const float*)d_in[1];
  const float* self_pe  = (const float*)d_in[2];
  const float* cross_pe = (const float*)d_in[3];
  const float* ln_qs_g = (const float*)d_in[4],  *ln_qs_b = (const float*)d_in[5];
  const float* ln_vs_g = (const float*)d_in[6],  *ln_vs_b = (const float*)d_in[7];
  const float* ln_qc_g = (const float*)d_in[8],  *ln_qc_b = (const float*)d_in[9];
  const float* ln_kv_g = (const float*)d_in[10], *ln_kv_b = (const float*)d_in[11];
  const float* ln_vc_g = (const float*)d_in[12], *ln_vc_b = (const float*)d_in[13];
  const float* ln_ffn_g = (const float*)d_in[14], *ln_ffn_b = (const float*)d_in[15];
  const float* Wq_s = (const float*)d_in[16], *Wk_s = (const float*)d_in[17];
  const float* Wv_s = (const float*)d_in[18], *Wp_s = (const float*)d_in[19];
  const float* Wq_c = (const float*)d_in[20], *Wk_c = (const float*)d_in[21];
  const float* Wv_c = (const float*)d_in[22], *Wp_c = (const float*)d_in[23];
  const float* bq_s = (const float*)d_in[24], *bv_s = (const float*)d_in[25];
  const float* bp_s = (const float*)d_in[26], *bq_c = (const float*)d_in[27];
  const float* bv_c = (const float*)d_in[28], *bp_c = (const float*)d_in[29];
  const float* W1 = (const float*)d_in[30], *b1 = (const float*)d_in[31];
  const float* W2 = (const float*)d_in[32], *b2 = (const float*)d_in[33];
  float* outp = (float*)d_out;
  char* ws = (char*)d_ws;

  // ---- workspace layout ----
  size_t off = 0;
  auto alloc = [&](size_t bytes) { size_t o = off; off = (off + bytes + 255) & ~(size_t)255; return o; };
  size_t QT  = alloc((size_t)BW_ * 2048 * 2);
  size_t CTX = alloc((size_t)BW_ * 2048 * 2);
  size_t MQK = alloc((size_t)2048 * 256 * 2);
  size_t MVP = alloc((size_t)256 * 2048 * 2);
  size_t BQK = alloc(2048 * 4);
  size_t BVP = alloc(256 * 4);
  size_t WQKVS = alloc((size_t)768 * 256 * 2);
  size_t BQKVS = alloc(768 * 4);
  size_t WPS = alloc(65536 * 2);
  size_t W1T = alloc(262144 * 2), W2T = alloc(262144 * 2);
  size_t QN_C = alloc((size_t)BW_ * C_ * 2);
  size_t PES  = alloc(64 * 4);
  size_t X1    = alloc((size_t)BW_ * C_ * 4);
  size_t QN_S  = alloc((size_t)BW_ * C_ * 2);
  size_t VN_S  = alloc((size_t)BW_ * C_ * 2);
  size_t QKV_S = alloc((size_t)BW_ * 768 * 4);
  size_t S_O   = alloc((size_t)BW_ * C_ * 2);
  size_t X2    = alloc((size_t)BW_ * C_ * 4);
  size_t FFN   = alloc((size_t)BW_ * C_ * 2);
  size_t H1    = alloc((size_t)BW_ * F_ * 2);

  unsigned short* qt   = (unsigned short*)(ws + QT);
  unsigned short* ctx  = (unsigned short*)(ws + CTX);
  unsigned short* mqk  = (unsigned short*)(ws + MQK);
  unsigned short* mvp  = (unsigned short*)(ws + MVP);
  float* bqk = (float*)(ws + BQK);
  float* bvp = (float*)(ws + BVP);
  unsigned short* wqkvs = (unsigned short*)(ws + WQKVS);
  float* bqkvs = (float*)(ws + BQKVS);
  unsigned short* wps = (unsigned short*)(ws + WPS);
  unsigned short* w1t = (unsigned short*)(ws + W1T), *w2t = (unsigned short*)(ws + W2T);
  unsigned short* qn_c = (unsigned short*)(ws + QN_C);
  float* pes = (float*)(ws + PES);
  float*          x1   = (float*)(ws + X1);
  unsigned short* qn_s = (unsigned short*)(ws + QN_S);
  unsigned short* vn_s = (unsigned short*)(ws + VN_S);
  float* qkv_s = (float*)(ws + QKV_S);
  unsigned short* s_o  = (unsigned short*)(ws + S_O);
  float*          x2   = (float*)(ws + X2);
  unsigned short* ffn_n = (unsigned short*)(ws + FFN);
  unsigned short* h1    = (unsigned short*)(ws + H1);

  // 1. all prep (weights, folded matrices, LN(pooled), pe sums) in one launch
  prep_all<<<6018, 256, 0, stream>>>(
      Wq_s, Wk_s, Wv_s, Wp_s, W1, W2, Wq_c, Wk_c, Wv_c, Wp_c,
      bq_s, bv_s, bq_c, bv_c, bp_c, pooled, ln_qc_g, ln_qc_b, cross_pe,
      wqkvs, wps, w1t, w2t, mqk, mvp, bqk, bvp, bqkvs, qn_c, pes);

  // 2. q~ = qn_c @ Mqk^T + bqk
  gemm_bt<<<(BW_ / 64) * (2048 / 64), 256, 0, stream>>>(qn_c, mqk, BW_, 2048, 256,
      bqk, nullptr, nullptr, qt, 0);

  // 3. fused LN-transpose + cross attention (features -> ctx, no kn/vn)
  cross_fused<<<528, 256, 0, stream>>>(features, cross_pe, qt,
      ln_kv_g, ln_kv_b, ln_vc_g, ln_vc_b, pes, ctx);

  // 4. x1 = ctx @ Mvp^T + bvp + pooled
  gemm_bt<<<(BW_ / 64) * (C_ / 64), 256, 0, stream>>>(ctx, mvp, BW_, C_, 2048,
      bvp, pooled, x1, nullptr, 0);

  // 5. qn_s = LN(x1+self_pe), vn_s = LN(x1)
  ln_dual<<<BW_, 256, 0, stream>>>(x1, self_pe, ln_qs_g, ln_qs_b,
                                   ln_vs_g, ln_vs_b, qn_s, vn_s);

  // 6. q|k from qn_s -> qkv_s cols [0,512); v from vn_s -> cols [512,768). ldc=768.
  gemm_bt_st<<<(BW_ / 64) * (512 / 64), 256, 0, stream>>>(qn_s, wqkvs, BW_, 512, 256,
      768, bqkvs, qkv_s);
  gemm_bt_st<<<(BW_ / 64) * (256 / 64), 256, 0, stream>>>(vn_s, wqkvs + 131072, BW_, 256, 256,
      768, bqkvs + 512, qkv_s + 512);

  // 7. self attention core
  self_attn3<<<B_ * 8, 192, 0, stream>>>(qkv_s, s_o);

  // 8. x2 = s_o @ Wp_s + bp_s + x1
  gemm_bt<<<(BW_ / 64) * (C_ / 64), 256, 0, stream>>>(s_o, wps, BW_, C_, C_,
      bp_s, x1, x2, nullptr, 0);

  // 9. FFN
  ln_rows<<<BW_, 256, 0, stream>>>(x2, ln_ffn_g, ln_ffn_b, ffn_n);
  gemm_bt<<<(BW_ / 64) * (F_ / 64), 256, 0, stream>>>(ffn_n, w1t, BW_, F_, C_,
      b1, nullptr, nullptr, h1, 1);
  gemm_bt<<<(BW_ / 64) * (C_ / 64), 256, 0, stream>>>(h1, w2t, BW_, C_, F_,
      b2, x2, outp, nullptr, 0);
}